// Round 14
// baseline (1315.974 us; speedup 1.0000x reference)
//
#include <hip/hip_runtime.h>
#include <math.h>

#define N_NODES 100000
#define N_EDGES 1600000

static constexpr int GG = (N_NODES + 63) / 64;          // 1563
static constexpr int NB = (N_NODES + 255) / 256;        // 391 dense blocks
static constexpr int NBKT = (N_NODES + 255) / 256;      // 391 buckets (dst >> 8)

typedef __attribute__((ext_vector_type(8))) short          bf16x8;
typedef __attribute__((ext_vector_type(8))) unsigned short ushort8_t;
typedef __attribute__((ext_vector_type(4))) unsigned short ushort4_t;
typedef __attribute__((ext_vector_type(4))) float          f32x4;
typedef __attribute__((ext_vector_type(4))) unsigned       uint4v;

__device__ __forceinline__ float lrelu(float v, float s){ return v >= 0.f ? v : v*s; }

__device__ __forceinline__ unsigned short f2bf(float f){
    unsigned u = __float_as_uint(f);
    unsigned r = (u + 0x7FFFu + ((u >> 16) & 1u)) >> 16;   // RNE
    return (unsigned short)r;
}
__device__ __forceinline__ float bf2f(unsigned short h){
    return __uint_as_float(((unsigned)h) << 16);
}
// packed hi|lo<<16 bf16 pair of an f32 (hi + lo represents f to ~2^-17 rel)
__device__ __forceinline__ unsigned packhl(float f){
    unsigned short hi = f2bf(f);
    unsigned short lo = f2bf(f - bf2f(hi));
    return (unsigned)hi | ((unsigned)lo << 16);
}
// 8 packed u32 -> hi-frag and lo-frag (bf16x8 each)
__device__ __forceinline__ void unpack8(const unsigned* q, bf16x8& ah, bf16x8& al){
    unsigned a32[4], l32[4];
#pragma unroll
    for (int k = 0; k < 4; k++) {
        a32[k] = (q[2*k] & 0xffffu) | (q[2*k+1] << 16);
        l32[k] = (q[2*k] >> 16)     | (q[2*k+1] & 0xffff0000u);
    }
    ah = *(const bf16x8*)a32;
    al = *(const bf16x8*)l32;
}

// ---------------- weight split: wt_hi/lo[n][k] = hi/lo bf16 of w[k][n] ----------------
__global__ void cvt_wT_split(const float* __restrict__ w,
                             unsigned short* __restrict__ whi,
                             unsigned short* __restrict__ wlo,
                             int K, int Nsrc, int Npad)
{
    int idx = blockIdx.x * 256 + threadIdx.x;
    if (idx >= Npad * K) return;
    int n = idx / K, k = idx % K;
    float v = (n < Nsrc) ? w[(long)k * Nsrc + n] : 0.f;
    unsigned short hi = f2bf(v);
    whi[idx] = hi;
    wlo[idx] = f2bf(v - bf2f(hi));
}

// ---------------- fully-fused MLP (round-11 config: 64 rows, packed hi/lo u32) --------
__global__ __launch_bounds__(256) void mlp_fused(
    const float* __restrict__ x,
    const unsigned short* __restrict__ w1h, const unsigned short* __restrict__ w1l,
    const float* __restrict__ b1,
    const unsigned short* __restrict__ w2h, const unsigned short* __restrict__ w2l,
    const float* __restrict__ b2,
    const unsigned short* __restrict__ w3h, const unsigned short* __restrict__ w3l,
    const float* __restrict__ b3,
    float* __restrict__ XtOut)
{
    constexpr int AS = 260;
    __shared__ unsigned h_pk[64 * AS];          // 66.6 KB
    const int t = threadIdx.x;
    const int r0 = blockIdx.x * 64;
    const int wv = t >> 6, lane = t & 63;
    const int l15 = lane & 15, grp = lane >> 4;
    const int cw = wv * 64;

    // ---- stage x (64 rows x 64 f32) as packed hi/lo ----
    {
        int c = t;
#pragma unroll
        for (int it = 0; it < 4; it++, c += 256) {   // 1024 float4 chunks
            int row = c >> 4, kq = c & 15;
            int gr = r0 + row;
            float4 v = make_float4(0.f, 0.f, 0.f, 0.f);
            if (gr < N_NODES) v = *(const float4*)(x + (long)gr * 64 + kq * 4);
            unsigned p[4] = {packhl(v.x), packhl(v.y), packhl(v.z), packhl(v.w)};
            *(uint4v*)(h_pk + row * AS + kq * 4) = *(const uint4v*)p;
        }
    }
    __syncthreads();

    f32x4 acc[4][4];

    // ---- layer 1: K=64 ----
#pragma unroll
    for (int i = 0; i < 4; i++)
#pragma unroll
        for (int j = 0; j < 4; j++) acc[i][j] = (f32x4){0.f,0.f,0.f,0.f};
#pragma unroll
    for (int ks = 0; ks < 2; ks++) {
        bf16x8 ah[4], al[4], bh[4], bl[4];
#pragma unroll
        for (int i = 0; i < 4; i++) {
            unsigned q[8];
            const unsigned* p = h_pk + (i*16 + l15) * AS + ks*32 + grp*8;
            *(uint4v*)q     = *(const uint4v*)p;
            *(uint4v*)(q+4) = *(const uint4v*)(p + 4);
            unpack8(q, ah[i], al[i]);
        }
#pragma unroll
        for (int j = 0; j < 4; j++) {
            const size_t bo = (size_t)(cw + j*16 + l15) * 64 + ks*32 + grp*8;
            bh[j] = *(const bf16x8*)(w1h + bo);
            bl[j] = *(const bf16x8*)(w1l + bo);
        }
#pragma unroll
        for (int i = 0; i < 4; i++)
#pragma unroll
            for (int j = 0; j < 4; j++) {
                acc[i][j] = __builtin_amdgcn_mfma_f32_16x16x32_bf16(ah[i], bl[j], acc[i][j], 0, 0, 0);
                acc[i][j] = __builtin_amdgcn_mfma_f32_16x16x32_bf16(al[i], bh[j], acc[i][j], 0, 0, 0);
                acc[i][j] = __builtin_amdgcn_mfma_f32_16x16x32_bf16(ah[i], bh[j], acc[i][j], 0, 0, 0);
            }
    }
    __syncthreads();   // all L1 reads done before overwrite
#pragma unroll
    for (int i = 0; i < 4; i++)
#pragma unroll
        for (int j = 0; j < 4; j++) {
            int col = cw + j*16 + l15;
            float bv = b1[col];
#pragma unroll
            for (int r = 0; r < 4; r++) {
                int row = i*16 + grp*4 + r;
                h_pk[row * AS + col] = packhl(lrelu(acc[i][j][r] + bv, 0.01f));
            }
        }
    __syncthreads();

    // ---- layer 2: K=256 ----
#pragma unroll
    for (int i = 0; i < 4; i++)
#pragma unroll
        for (int j = 0; j < 4; j++) acc[i][j] = (f32x4){0.f,0.f,0.f,0.f};
#pragma unroll
    for (int ks = 0; ks < 8; ks++) {
        bf16x8 ah[4], al[4], bh[4], bl[4];
#pragma unroll
        for (int i = 0; i < 4; i++) {
            unsigned q[8];
            const unsigned* p = h_pk + (i*16 + l15) * AS + ks*32 + grp*8;
            *(uint4v*)q     = *(const uint4v*)p;
            *(uint4v*)(q+4) = *(const uint4v*)(p + 4);
            unpack8(q, ah[i], al[i]);
        }
#pragma unroll
        for (int j = 0; j < 4; j++) {
            const size_t bo = (size_t)(cw + j*16 + l15) * 256 + ks*32 + grp*8;
            bh[j] = *(const bf16x8*)(w2h + bo);
            bl[j] = *(const bf16x8*)(w2l + bo);
        }
#pragma unroll
        for (int i = 0; i < 4; i++)
#pragma unroll
            for (int j = 0; j < 4; j++) {
                acc[i][j] = __builtin_amdgcn_mfma_f32_16x16x32_bf16(ah[i], bl[j], acc[i][j], 0, 0, 0);
                acc[i][j] = __builtin_amdgcn_mfma_f32_16x16x32_bf16(al[i], bh[j], acc[i][j], 0, 0, 0);
                acc[i][j] = __builtin_amdgcn_mfma_f32_16x16x32_bf16(ah[i], bh[j], acc[i][j], 0, 0, 0);
            }
    }
    __syncthreads();
#pragma unroll
    for (int i = 0; i < 4; i++)
#pragma unroll
        for (int j = 0; j < 4; j++) {
            int col = cw + j*16 + l15;
            float bv = b2[col];
#pragma unroll
            for (int r = 0; r < 4; r++) {
                int row = i*16 + grp*4 + r;
                h_pk[row * AS + col] = packhl(lrelu(acc[i][j][r] + bv, 0.01f));
            }
        }
    __syncthreads();

    // ---- layer 3: K=256 -> 24 cols; wave wv owns rows wv*16..+15 ----
    f32x4 acc3[2] = {(f32x4){0.f,0.f,0.f,0.f}, (f32x4){0.f,0.f,0.f,0.f}};
#pragma unroll
    for (int ks = 0; ks < 8; ks++) {
        unsigned q[8];
        const unsigned* p = h_pk + (wv*16 + l15) * AS + ks*32 + grp*8;
        *(uint4v*)q     = *(const uint4v*)p;
        *(uint4v*)(q+4) = *(const uint4v*)(p + 4);
        bf16x8 ah, al;
        unpack8(q, ah, al);
#pragma unroll
        for (int j = 0; j < 2; j++) {
            const size_t bo = (size_t)(j*16 + l15) * 256 + ks*32 + grp*8;
            bf16x8 bh = *(const bf16x8*)(w3h + bo);
            bf16x8 bl = *(const bf16x8*)(w3l + bo);
            acc3[j] = __builtin_amdgcn_mfma_f32_16x16x32_bf16(ah, bl, acc3[j], 0, 0, 0);
            acc3[j] = __builtin_amdgcn_mfma_f32_16x16x32_bf16(al, bh, acc3[j], 0, 0, 0);
            acc3[j] = __builtin_amdgcn_mfma_f32_16x16x32_bf16(ah, bh, acc3[j], 0, 0, 0);
        }
    }
    __syncthreads();   // all L3 reads done; reuse LDS as f32 out-stage
    float* ldsf = (float*)h_pk;   // [64][25]
#pragma unroll
    for (int j = 0; j < 2; j++)
#pragma unroll
        for (int r = 0; r < 4; r++) {
            int cl = j*16 + l15;
            if (cl < 24) {
                int rl = wv*16 + grp*4 + r;
                ldsf[rl * 25 + cl] = lrelu(acc3[j][r] + b3[cl], 0.01f);
            }
        }
    __syncthreads();
    int n = t & 63, c0 = t >> 6;
    int gr = r0 + n;
    if (gr < N_NODES)
        for (int c = c0; c < 24; c += 4)
            XtOut[(long)c * N_NODES + gr] = ldsf[n * 25 + c];
}

// ---------------- BN stats over channel-major layout (initial C0 channels) -------
__global__ void bn_stats_t(const float* __restrict__ Xt,
                           float* __restrict__ gsum, float* __restrict__ gsq)
{
    int ch = blockIdx.x, part = blockIdx.y, t = threadIdx.x;
    const float* p = Xt + (long)ch * N_NODES;
    float s = 0.f, q = 0.f;
    for (long i = (long)part * 25000 + t * 4; i < (long)(part + 1) * 25000; i += 1024) {
        float4 v = *(const float4*)(p + i);
        s += v.x + v.y + v.z + v.w;
        q += v.x*v.x + v.y*v.y + v.z*v.z + v.w*v.w;
    }
#pragma unroll
    for (int m = 1; m < 64; m <<= 1) {
        s += __shfl_xor(s, m, 64);
        q += __shfl_xor(q, m, 64);
    }
    __shared__ float ls[4], lq[4];
    int wid = t >> 6;
    if ((t & 63) == 0) { ls[wid] = s; lq[wid] = q; }
    __syncthreads();
    if (t == 0) {
        atomicAdd(gsum + ch, ls[0] + ls[1] + ls[2] + ls[3]);
        atomicAdd(gsq  + ch, lq[0] + lq[1] + lq[2] + lq[3]);
    }
}

// ---------------- densenet layer: 128 thr, 2 nodes/thread (float2 IO) ----------------
__global__ __launch_bounds__(128) void dense_conv2(
    float* __restrict__ Xt, int C, int C0, int layerIdx,
    const float* __restrict__ W, int WS,
    const float* __restrict__ gamma, const float* __restrict__ beta,
    const float* __restrict__ gsum, const float* __restrict__ gsq,
    float* __restrict__ psq)
{
    constexpr int QOFF = 6 * 12 * NB;
    __shared__ float w_lds[132 * 12];       // [c][g], 48B rows (16B aligned)
    __shared__ float a_lds[132], b_lds[132];
    __shared__ float red[2][2][12];
    const int t = threadIdx.x;
    const int wid = t >> 6, lane = t & 63;

    for (int c = t; c < C0; c += 128) {
        float s = gsum[c], q = gsq[c];
        float mu  = s * (1.f / N_NODES);
        float var = q * (1.f / N_NODES) - mu * mu;
        float A = rsqrtf(var + 1e-5f) * gamma[c];
        a_lds[c] = A;
        b_lds[c] = beta[c] - mu * A;
    }
    for (int gc = wid; gc < C - C0; gc += 2) {   // one wave per grown channel
        const float* pp = psq + (size_t)gc * NB;
        const float* qq = psq + QOFF + (size_t)gc * NB;
        float s = 0.f, q = 0.f;
        for (int b = lane; b < NB; b += 64) { s += pp[b]; q += qq[b]; }
#pragma unroll
        for (int o = 1; o < 64; o <<= 1) {
            s += __shfl_xor(s, o, 64);
            q += __shfl_xor(q, o, 64);
        }
        if (lane == 0) {
            int c = C0 + gc;
            float mu  = s * (1.f / N_NODES);
            float var = q * (1.f / N_NODES) - mu * mu;
            float A = rsqrtf(var + 1e-5f) * gamma[c];
            a_lds[c] = A;
            b_lds[c] = beta[c] - mu * A;
        }
    }
    for (int i = t; i < 12 * C; i += 128) {
        int g = i / C, c = i - g * C;
        w_lds[c * 12 + g] = W[g * WS + c];   // transposed
    }
    __syncthreads();

    long n0 = ((long)blockIdx.x * 128 + t) * 2;   // pair of nodes
    bool valid = (n0 < N_NODES);
    const float* xp = Xt + (valid ? n0 : 0);
    float2 acc[12];
#pragma unroll
    for (int g = 0; g < 12; g++) acc[g] = make_float2(0.f, 0.f);

    float2 v[12], vn[12];
#pragma unroll
    for (int j = 0; j < 12; j++) v[j] = *(const float2*)(xp + (long)j * N_NODES);
    for (int c0 = 0; c0 < C; c0 += 12) {
        if (c0 + 12 < C) {
#pragma unroll
            for (int j = 0; j < 12; j++)
                vn[j] = *(const float2*)(xp + (long)(c0 + 12 + j) * N_NODES);
        }
#pragma unroll
        for (int j = 0; j < 12; j++) {
            int ch = c0 + j;
            float Ac = a_lds[ch], Bc = b_lds[ch];
            float ux = lrelu(Ac * v[j].x + Bc, 0.01f);
            float uy = lrelu(Ac * v[j].y + Bc, 0.01f);
            const float4* wp = (const float4*)(w_lds + ch * 12);
            float4 w0 = wp[0], w1 = wp[1], w2 = wp[2];
            acc[0].x += ux*w0.x; acc[0].y += uy*w0.x;
            acc[1].x += ux*w0.y; acc[1].y += uy*w0.y;
            acc[2].x += ux*w0.z; acc[2].y += uy*w0.z;
            acc[3].x += ux*w0.w; acc[3].y += uy*w0.w;
            acc[4].x += ux*w1.x; acc[4].y += uy*w1.x;
            acc[5].x += ux*w1.y; acc[5].y += uy*w1.y;
            acc[6].x += ux*w1.z; acc[6].y += uy*w1.z;
            acc[7].x += ux*w1.w; acc[7].y += uy*w1.w;
            acc[8].x += ux*w2.x; acc[8].y += uy*w2.x;
            acc[9].x += ux*w2.y; acc[9].y += uy*w2.y;
            acc[10].x += ux*w2.z; acc[10].y += uy*w2.z;
            acc[11].x += ux*w2.w; acc[11].y += uy*w2.w;
        }
#pragma unroll
        for (int j = 0; j < 12; j++) v[j] = vn[j];
    }
    if (valid) {
#pragma unroll
        for (int g = 0; g < 12; g++)
            *(float2*)(Xt + (long)(C + g) * N_NODES + n0) = acc[g];
    }

    if (layerIdx < 5) {
        float sv[12], qv[12];
#pragma unroll
        for (int g = 0; g < 12; g++) {
            float ax = valid ? acc[g].x : 0.f;
            float ay = valid ? acc[g].y : 0.f;
            sv[g] = ax + ay; qv[g] = ax*ax + ay*ay;
        }
#pragma unroll
        for (int m = 1; m < 64; m <<= 1)
#pragma unroll
            for (int g = 0; g < 12; g++) {
                sv[g] += __shfl_xor(sv[g], m, 64);
                qv[g] += __shfl_xor(qv[g], m, 64);
            }
        if (lane == 0) {
#pragma unroll
            for (int g = 0; g < 12; g++) { red[0][wid][g] = sv[g]; red[1][wid][g] = qv[g]; }
        }
        __syncthreads();
        if (t < 12) {
            float s = red[0][0][t] + red[0][1][t];
            float q = red[1][0][t] + red[1][1][t];
            psq[((size_t)layerIdx * 12 + t) * NB + blockIdx.x] = s;
            psq[QOFF + ((size_t)layerIdx * 12 + t) * NB + blockIdx.x] = q;
        }
    }
}

// ---------------- GAT GEMM (f32-exact) + fused scores + bf16 H (stride 64) -------
template<int F>
__global__ __launch_bounds__(256) void gat_gemm(
    const float* __restrict__ A, const float* __restrict__ B,
    const float* __restrict__ avec, int K,
    unsigned short* __restrict__ Hb, float* __restrict__ sd, float* __restrict__ ss)
{
    __shared__ float At[16 * 68];
    __shared__ float Bt[16 * 64];
    __shared__ float ad[64], as_[64];
    const int t  = threadIdx.x;
    const int r0 = blockIdx.x * 64;
    const int tx = t & 15, ty = t >> 4;
    if (t < 64) {
        ad[t]  = (t < F) ? avec[t]     : 0.f;
        as_[t] = (t < F) ? avec[F + t] : 0.f;
    }

    float acc[4][4];
#pragma unroll
    for (int i = 0; i < 4; i++)
#pragma unroll
        for (int j = 0; j < 4; j++) acc[i][j] = 0.f;

    for (int k0 = 0; k0 < K; k0 += 16) {
        {
            int kk = t >> 4, rq = t & 15;
            float4 v = make_float4(0.f,0.f,0.f,0.f);
            if (k0 + kk < K)
                v = *(const float4*)(A + (long)(k0 + kk) * N_NODES + r0 + rq * 4);
            *(float4*)(At + kk * 68 + rq * 4) = v;
        }
        for (int i = t; i < 16 * 64; i += 256) {
            int kk = i >> 6, mq = i & 63;
            float v = 0.f;
            if (k0 + kk < K && mq < F) v = B[(long)(k0 + kk) * F + mq];
            Bt[kk * 64 + mq] = v;
        }
        __syncthreads();
#pragma unroll
        for (int kk = 0; kk < 16; kk++) {
            float4 av = *(const float4*)(At + kk * 68 + ty * 4);
            float4 bv = *(const float4*)(Bt + kk * 64 + tx * 4);
            float a_[4] = {av.x, av.y, av.z, av.w};
            float b_[4] = {bv.x, bv.y, bv.z, bv.w};
#pragma unroll
            for (int i = 0; i < 4; i++)
#pragma unroll
                for (int j = 0; j < 4; j++)
                    acc[i][j] += a_[i] * b_[j];
        }
        __syncthreads();
    }

#pragma unroll
    for (int i = 0; i < 4; i++) {
        int row = r0 + ty * 4 + i;
        float pd = 0.f, pq_ = 0.f;
#pragma unroll
        for (int j = 0; j < 4; j++) {
            int col = tx * 4 + j;
            pd  += acc[i][j] * ad[col];
            pq_ += acc[i][j] * as_[col];
        }
#pragma unroll
        for (int m = 1; m < 16; m <<= 1) {
            pd  += __shfl_xor(pd,  m, 64);
            pq_ += __shfl_xor(pq_, m, 64);
        }
        if (row < N_NODES) {
            if (tx == 0) { sd[row] = pd; ss[row] = pq_; }
            if (tx * 4 < F) {
                ushort4_t u;
#pragma unroll
                for (int j = 0; j < 4; j++) u[j] = f2bf(acc[i][j]);
                *(ushort4_t*)(Hb + (long)row * 64 + tx * 4) = u;
            }
        }
    }
}

// ---------------- fused GAT softmax+aggregate over CSR (8x-unrolled gather) -------
template<int F>
__global__ __launch_bounds__(256) void gat_aggregate2(
    const int* __restrict__ rstart, const int* __restrict__ csr_src,
    const float* __restrict__ sd, const float* __restrict__ ss,
    const unsigned short* __restrict__ Hb,
    const float* __restrict__ bias, float* __restrict__ outT)
{
    __shared__ float tile[64 * (F + 1)];
    const int t = threadIdx.x;
    const int wid = t >> 6, lane = t & 63;
    const long n0 = (long)blockIdx.x * 64;

#pragma unroll 1
    for (int k = 0; k < 16; k++) {
        long node = n0 + wid * 16 + k;
        float res = 0.f;
        if (node < N_NODES) {
            int st = rstart[node], en = rstart[node + 1];
            int deg = en - st;
            float sdn = sd[node];
            float acc = 0.f, dsum = 0.f;
            if (deg <= 64) {
                int sj = 0; float v = -3.4e38f;
                if (lane < deg) {
                    sj = csr_src[st + lane];
                    v = lrelu(sdn + ss[sj], 0.2f);
                }
                float m = v;
#pragma unroll
                for (int o = 1; o < 64; o <<= 1) m = fmaxf(m, __shfl_xor(m, o, 64));
                float p = (lane < deg) ? __expf(v - m) : 0.f;
                dsum = p;
                int j = 0;
                for (; j + 8 <= deg; j += 8) {   // 8 outstanding gathers
                    float a_[8]; int s_[8];
#pragma unroll
                    for (int u = 0; u < 8; u++) {
                        a_[u] = __shfl(p, j + u, 64);
                        s_[u] = __shfl(sj, j + u, 64);
                    }
                    if (lane < F) {
                        float h_[8];
#pragma unroll
                        for (int u = 0; u < 8; u++)
                            h_[u] = bf2f(Hb[(long)s_[u] * 64 + lane]);
#pragma unroll
                        for (int u = 0; u < 8; u++)
                            acc += a_[u] * h_[u];
                    }
                }
                for (; j < deg; j++) {
                    float a = __shfl(p, j, 64);
                    int   s = __shfl(sj, j, 64);
                    if (lane < F) acc += a * bf2f(Hb[(long)s * 64 + lane]);
                }
            } else {
                float m = -3.4e38f;
                for (int base = st; base < en; base += 64) {
                    int cnt = min(64, en - base);
                    float v = -3.4e38f;
                    if (lane < cnt) {
                        int s = csr_src[base + lane];
                        v = lrelu(sdn + ss[s], 0.2f);
                    }
#pragma unroll
                    for (int o = 1; o < 64; o <<= 1) v = fmaxf(v, __shfl_xor(v, o, 64));
                    m = fmaxf(m, v);
                }
                for (int base = st; base < en; base += 64) {
                    int cnt = min(64, en - base);
                    float p = 0.f; int sj = 0;
                    if (lane < cnt) {
                        sj = csr_src[base + lane];
                        float v = lrelu(sdn + ss[sj], 0.2f);
                        p = __expf(v - m);
                    }
                    dsum += p;
                    int j = 0;
                    for (; j + 8 <= cnt; j += 8) {
                        float a_[8]; int s_[8];
#pragma unroll
                        for (int u = 0; u < 8; u++) {
                            a_[u] = __shfl(p, j + u, 64);
                            s_[u] = __shfl(sj, j + u, 64);
                        }
                        if (lane < F) {
                            float h_[8];
#pragma unroll
                            for (int u = 0; u < 8; u++)
                                h_[u] = bf2f(Hb[(long)s_[u] * 64 + lane]);
#pragma unroll
                            for (int u = 0; u < 8; u++)
                                acc += a_[u] * h_[u];
                        }
                    }
                    for (; j < cnt; j++) {
                        float a = __shfl(p, j, 64);
                        int   s = __shfl(sj, j, 64);
                        if (lane < F) acc += a * bf2f(Hb[(long)s * 64 + lane]);
                    }
                }
            }
#pragma unroll
            for (int o = 1; o < 64; o <<= 1) dsum += __shfl_xor(dsum, o, 64);
            res = acc / (dsum + 1e-16f);
        }
        if (lane < F) tile[(wid * 16 + k) * (F + 1) + lane] = res + bias[lane];
    }
    __syncthreads();
    for (int idx = t; idx < F * 64; idx += 256) {
        int c = idx / 64, i = idx % 64;
        long n = n0 + i;
        if (n < N_NODES) outT[(long)c * N_NODES + n] = tile[i * (F + 1) + c];
    }
}

// ---------------- final transpose [132][N] -> [N,132] ----------------
__global__ __launch_bounds__(256) void transpose_out(const float* __restrict__ Xt,
                                                     float* __restrict__ out)
{
    __shared__ float tile[64 * 133];
    int t = threadIdx.x;
    long n0 = (long)blockIdx.x * 64;
    int lane = t & 63, cq = t >> 6;
    for (int c = cq; c < 132; c += 4) {
        long n = n0 + lane;
        float v = (n < N_NODES) ? Xt[(long)c * N_NODES + n] : 0.f;
        tile[lane * 133 + c] = v;
    }
    __syncthreads();
    for (int idx = t; idx < 64 * 132; idx += 256) {
        int r = idx / 132, c = idx % 132;
        long n = n0 + r;
        if (n < N_NODES) out[n * 132 + c] = tile[r * 133 + c];
    }
}

// ---------------- bucket-sorted CSR build ----------------
__global__ __launch_bounds__(256) void bkt_hist(const int* __restrict__ dst,
                                                int* __restrict__ bcnt)
{
    __shared__ int lh[NBKT];
    for (int i = threadIdx.x; i < NBKT; i += 256) lh[i] = 0;
    __syncthreads();
    for (long e = (long)blockIdx.x * 256 + threadIdx.x; e < N_EDGES; e += (long)gridDim.x * 256)
        atomicAdd(&lh[dst[e] >> 8], 1);
    __syncthreads();
    for (int i = threadIdx.x; i < NBKT; i += 256)
        if (lh[i]) atomicAdd(&bcnt[i * 16], lh[i]);
}

__global__ void bkt_scan(const int* __restrict__ bcnt, int* __restrict__ boff,
                         int* __restrict__ bcur, int* __restrict__ rstart)
{
    __shared__ int ls[512];
    int t = threadIdx.x;
    int v = (t < NBKT) ? bcnt[t * 16] : 0;
    ls[t] = v; __syncthreads();
    for (int o = 1; o < 512; o <<= 1) {
        int y = (t >= o) ? ls[t - o] : 0;
        __syncthreads();
        ls[t] += y;
        __syncthreads();
    }
    if (t < NBKT) { int ex = ls[t] - v; boff[t] = ex; bcur[t * 16] = ex; }
    if (t == 0) { boff[NBKT] = N_EDGES; rstart[N_NODES] = N_EDGES; }
}

__global__ void bkt_scatter(const int* __restrict__ src, const int* __restrict__ dst,
                            int* __restrict__ bcur, int2* __restrict__ pairs)
{
    for (long e = (long)blockIdx.x * 256 + threadIdx.x; e < N_EDGES; e += (long)gridDim.x * 256) {
        int d = dst[e];
        int pos = atomicAdd(&bcur[(d >> 8) * 16], 1);
        pairs[pos] = make_int2(d, src[e]);
    }
}

__global__ __launch_bounds__(256) void bkt_build(const int2* __restrict__ pairs,
                                                 const int* __restrict__ boff,
                                                 int* __restrict__ rstart,
                                                 int* __restrict__ csr_src)
{
    __shared__ int lh[256], sc[256], lbase[256], lcur[256];
    int b = blockIdx.x, t = threadIdx.x;
    int st = boff[b], en = boff[b + 1];
    lh[t] = 0;
    __syncthreads();
    for (int i = st + t; i < en; i += 256)
        atomicAdd(&lh[pairs[i].x & 255], 1);
    __syncthreads();
    int v = lh[t];
    sc[t] = v; __syncthreads();
    for (int o = 1; o < 256; o <<= 1) {
        int y = (t >= o) ? sc[t - o] : 0;
        __syncthreads();
        sc[t] += y;
        __syncthreads();
    }
    int ex = sc[t] - v;
    lbase[t] = st + ex;
    lcur[t] = 0;
    int node = (b << 8) + t;
    if (node < N_NODES) rstart[node] = st + ex;
    __syncthreads();
    for (int i = st + t; i < en; i += 256) {
        int2 p = pairs[i];
        int ld = p.x & 255;
        int pos = lbase[ld] + atomicAdd(&lcur[ld], 1);
        csr_src[pos] = p.y;
    }
}

// ---------------- host helpers ----------------
static void run_dense_block_t(hipStream_t stream, float* Xt, int C0,
                              const float* convW, int WS,
                              const float* gamma, const float* beta,
                              float* gsum, float* gsq, float* psq)
{
    hipMemsetAsync(gsum, 0, 264 * sizeof(float), stream);
    bn_stats_t<<<dim3(C0, 4), 256, 0, stream>>>(Xt, gsum, gsq);
    for (int i = 0; i < 6; i++) {
        int C = C0 + 12 * i;
        dense_conv2<<<NB, 128, 0, stream>>>(Xt, C, C0, i, convW + (size_t)i * 12 * WS, WS,
                                            gamma + (size_t)i * WS, beta + (size_t)i * WS,
                                            gsum, gsq, psq);
    }
}

template<int F>
static void run_gat(hipStream_t stream, const float* XtIn, int K,
                    const float* W, const float* avec, const float* bias,
                    unsigned short* Hb, float* outT,
                    float* sd, float* ss, const int* rstart, const int* csr_src)
{
    gat_gemm<F><<<GG, 256, 0, stream>>>(XtIn, W, avec, K, Hb, sd, ss);
    gat_aggregate2<F><<<GG, 256, 0, stream>>>(rstart, csr_src, sd, ss, Hb, bias, outT);
}

extern "C" void kernel_launch(void* const* d_in, const int* in_sizes, int n_in,
                              void* d_out, int out_size, void* d_ws, size_t ws_size,
                              hipStream_t stream)
{
    const float* x     = (const float*)d_in[0];
    const int*   src   = (const int*)d_in[1];
    const int*   dst   = (const int*)d_in[2];
    const float* w1    = (const float*)d_in[3];
    const float* b1    = (const float*)d_in[4];
    const float* w2    = (const float*)d_in[5];
    const float* b2    = (const float*)d_in[6];
    const float* w3    = (const float*)d_in[7];
    const float* b3    = (const float*)d_in[8];
    const float* conv1 = (const float*)d_in[9];
    const float* bn1g  = (const float*)d_in[10];
    const float* bn1b  = (const float*)d_in[11];
    const float* g1w   = (const float*)d_in[12];
    const float* g1a   = (const float*)d_in[13];
    const float* g1b   = (const float*)d_in[14];
    const float* conv2 = (const float*)d_in[15];
    const float* bn2g  = (const float*)d_in[16];
    const float* bn2b  = (const float*)d_in[17];
    const float* g2w   = (const float*)d_in[18];
    const float* g2a   = (const float*)d_in[19];
    const float* g2b   = (const float*)d_in[20];
    const float* conv3 = (const float*)d_in[21];
    const float* bn3g  = (const float*)d_in[22];
    const float* bn3b  = (const float*)d_in[23];
    float* out = (float*)d_out;

    char* ws = (char*)d_ws;
    size_t off = 0;
    auto alloc = [&](size_t bytes) -> void* {
        void* p = ws + off;
        off += (bytes + 255) & ~(size_t)255;
        return p;
    };
    float*    h      = (float*)alloc((size_t)N_NODES * 256 * 4); // overlays: Hb + Xt3
    float*    Xt1    = (float*)alloc((size_t)96  * N_NODES * 4);
    float*    Xt2    = (float*)alloc((size_t)120 * N_NODES * 4);
    int*      csr_src= (int*)alloc((size_t)N_EDGES * 4);
    int2*     pairs  = (int2*)alloc((size_t)N_EDGES * 8);
    int*      rstart = (int*)alloc((size_t)(N_NODES + 1) * 4);
    int*      bcnt   = (int*)alloc((size_t)NBKT * 16 * 4);
    int*      bcur   = (int*)alloc((size_t)NBKT * 16 * 4);
    int*      boff   = (int*)alloc((size_t)(NBKT + 1) * 4);
    float*    sd     = (float*)alloc((size_t)N_NODES * 4);
    float*    ss     = (float*)alloc((size_t)N_NODES * 4);
    float*    gsum   = (float*)alloc(264 * 4);
    float*    gsq    = gsum + 132;
    float*    psq    = (float*)alloc((size_t)2 * 6 * 12 * NB * 4);
    unsigned short* wt1h = (unsigned short*)alloc(256 * 64  * 2);
    unsigned short* wt1l = (unsigned short*)alloc(256 * 64  * 2);
    unsigned short* wt2h = (unsigned short*)alloc(256 * 256 * 2);
    unsigned short* wt2l = (unsigned short*)alloc(256 * 256 * 2);
    unsigned short* wt3h = (unsigned short*)alloc(32  * 256 * 2);
    unsigned short* wt3l = (unsigned short*)alloc(32  * 256 * 2);

    // overlays in h (102.4 MB):
    unsigned short* Hb  = (unsigned short*)h;            // [N][64] bf16 = 12.8 MB (128B rows)
    float* Xt3 = (float*)((char*)h + (size_t)16 * 1024 * 1024); // [132][N] f32 = 52.8 MB

    // ---- bucket-sorted CSR by dst (shared by both GATs), payload = src values ----
    hipMemsetAsync(bcnt, 0, (size_t)NBKT * 16 * 4, stream);
    bkt_hist<<<512, 256, 0, stream>>>(dst, bcnt);
    bkt_scan<<<1, 512, 0, stream>>>(bcnt, boff, bcur, rstart);
    bkt_scatter<<<2048, 256, 0, stream>>>(src, dst, bcur, pairs);
    bkt_build<<<NBKT, 256, 0, stream>>>(pairs, boff, rstart, csr_src);

    // ---- weight prep (f32 -> transposed hi/lo bf16) ----
    cvt_wT_split<<<(256 * 64  + 255) / 256, 256, 0, stream>>>(w1, wt1h, wt1l, 64,  256, 256);
    cvt_wT_split<<<(256 * 256 + 255) / 256, 256, 0, stream>>>(w2, wt2h, wt2l, 256, 256, 256);
    cvt_wT_split<<<(32  * 256 + 255) / 256, 256, 0, stream>>>(w3, wt3h, wt3l, 256, 24,  32);

    // ---- fully-fused MLP (x -> L1 -> L2 -> L3 -> Xt1, activations stay in LDS) ----
    mlp_fused<<<GG, 256, 0, stream>>>(x, wt1h, wt1l, b1, wt2h, wt2l, b2,
                                      wt3h, wt3l, b3, Xt1);

    // ---- dense block 1 (24 -> 96, channel-major) ----
    run_dense_block_t(stream, Xt1, 24, conv1, 84, bn1g, bn1b, gsum, gsq, psq);

    // ---- GAT 1 (96 -> 48), output transposed into Xt2 rows 0..47 ----
    run_gat<48>(stream, Xt1, 96, g1w, g1a, g1b, Hb, Xt2, sd, ss, rstart, csr_src);

    // ---- dense block 2 (48 -> 120) ----
    run_dense_block_t(stream, Xt2, 48, conv2, 108, bn2g, bn2b, gsum, gsq, psq);

    // ---- GAT 2 (120 -> 60), output transposed into Xt3 rows 0..59 ----
    run_gat<60>(stream, Xt2, 120, g2w, g2a, g2b, Hb, Xt3, sd, ss, rstart, csr_src);

    // ---- dense block 3 (60 -> 132) ----
    run_dense_block_t(stream, Xt3, 60, conv3, 120, bn3g, bn3b, gsum, gsq, psq);

    // ---- final transpose to row-major d_out ----
    transpose_out<<<GG, 256, 0, stream>>>(Xt3, out);
}

// Round 15
// 1037.501 us; speedup vs baseline: 1.2684x; 1.2684x over previous
//
#include <hip/hip_runtime.h>
#include <math.h>

#define N_NODES 100000
#define N_EDGES 1600000

static constexpr int GG = (N_NODES + 63) / 64;          // 1563
static constexpr int NB = (N_NODES + 255) / 256;        // 391 dense blocks
static constexpr int NBKT = (N_NODES + 255) / 256;      // 391 buckets (dst >> 8)

typedef __attribute__((ext_vector_type(8))) short          bf16x8;
typedef __attribute__((ext_vector_type(8))) unsigned short ushort8_t;
typedef __attribute__((ext_vector_type(4))) unsigned short ushort4_t;
typedef __attribute__((ext_vector_type(4))) float          f32x4;
typedef __attribute__((ext_vector_type(4))) unsigned       uint4v;

__device__ __forceinline__ float lrelu(float v, float s){ return v >= 0.f ? v : v*s; }

__device__ __forceinline__ unsigned short f2bf(float f){
    unsigned u = __float_as_uint(f);
    unsigned r = (u + 0x7FFFu + ((u >> 16) & 1u)) >> 16;   // RNE
    return (unsigned short)r;
}
__device__ __forceinline__ float bf2f(unsigned short h){
    return __uint_as_float(((unsigned)h) << 16);
}
// packed hi|lo<<16 bf16 pair of an f32 (hi + lo represents f to ~2^-17 rel)
__device__ __forceinline__ unsigned packhl(float f){
    unsigned short hi = f2bf(f);
    unsigned short lo = f2bf(f - bf2f(hi));
    return (unsigned)hi | ((unsigned)lo << 16);
}
// 8 packed u32 -> hi-frag and lo-frag (bf16x8 each)
__device__ __forceinline__ void unpack8(const unsigned* q, bf16x8& ah, bf16x8& al){
    unsigned a32[4], l32[4];
#pragma unroll
    for (int k = 0; k < 4; k++) {
        a32[k] = (q[2*k] & 0xffffu) | (q[2*k+1] << 16);
        l32[k] = (q[2*k] >> 16)     | (q[2*k+1] & 0xffff0000u);
    }
    ah = *(const bf16x8*)a32;
    al = *(const bf16x8*)l32;
}

// ---------------- weight split: wt_hi/lo[n][k] = hi/lo bf16 of w[k][n] ----------------
__global__ void cvt_wT_split(const float* __restrict__ w,
                             unsigned short* __restrict__ whi,
                             unsigned short* __restrict__ wlo,
                             int K, int Nsrc, int Npad)
{
    int idx = blockIdx.x * 256 + threadIdx.x;
    if (idx >= Npad * K) return;
    int n = idx / K, k = idx % K;
    float v = (n < Nsrc) ? w[(long)k * Nsrc + n] : 0.f;
    unsigned short hi = f2bf(v);
    whi[idx] = hi;
    wlo[idx] = f2bf(v - bf2f(hi));
}

// ---------------- fully-fused MLP (round-11 config: 64 rows, packed hi/lo u32) --------
__global__ __launch_bounds__(256) void mlp_fused(
    const float* __restrict__ x,
    const unsigned short* __restrict__ w1h, const unsigned short* __restrict__ w1l,
    const float* __restrict__ b1,
    const unsigned short* __restrict__ w2h, const unsigned short* __restrict__ w2l,
    const float* __restrict__ b2,
    const unsigned short* __restrict__ w3h, const unsigned short* __restrict__ w3l,
    const float* __restrict__ b3,
    float* __restrict__ XtOut)
{
    constexpr int AS = 260;
    __shared__ unsigned h_pk[64 * AS];          // 66.6 KB
    const int t = threadIdx.x;
    const int r0 = blockIdx.x * 64;
    const int wv = t >> 6, lane = t & 63;
    const int l15 = lane & 15, grp = lane >> 4;
    const int cw = wv * 64;

    // ---- stage x (64 rows x 64 f32) as packed hi/lo ----
    {
        int c = t;
#pragma unroll
        for (int it = 0; it < 4; it++, c += 256) {   // 1024 float4 chunks
            int row = c >> 4, kq = c & 15;
            int gr = r0 + row;
            float4 v = make_float4(0.f, 0.f, 0.f, 0.f);
            if (gr < N_NODES) v = *(const float4*)(x + (long)gr * 64 + kq * 4);
            unsigned p[4] = {packhl(v.x), packhl(v.y), packhl(v.z), packhl(v.w)};
            *(uint4v*)(h_pk + row * AS + kq * 4) = *(const uint4v*)p;
        }
    }
    __syncthreads();

    f32x4 acc[4][4];

    // ---- layer 1: K=64 ----
#pragma unroll
    for (int i = 0; i < 4; i++)
#pragma unroll
        for (int j = 0; j < 4; j++) acc[i][j] = (f32x4){0.f,0.f,0.f,0.f};
#pragma unroll
    for (int ks = 0; ks < 2; ks++) {
        bf16x8 ah[4], al[4], bh[4], bl[4];
#pragma unroll
        for (int i = 0; i < 4; i++) {
            unsigned q[8];
            const unsigned* p = h_pk + (i*16 + l15) * AS + ks*32 + grp*8;
            *(uint4v*)q     = *(const uint4v*)p;
            *(uint4v*)(q+4) = *(const uint4v*)(p + 4);
            unpack8(q, ah[i], al[i]);
        }
#pragma unroll
        for (int j = 0; j < 4; j++) {
            const size_t bo = (size_t)(cw + j*16 + l15) * 64 + ks*32 + grp*8;
            bh[j] = *(const bf16x8*)(w1h + bo);
            bl[j] = *(const bf16x8*)(w1l + bo);
        }
#pragma unroll
        for (int i = 0; i < 4; i++)
#pragma unroll
            for (int j = 0; j < 4; j++) {
                acc[i][j] = __builtin_amdgcn_mfma_f32_16x16x32_bf16(ah[i], bl[j], acc[i][j], 0, 0, 0);
                acc[i][j] = __builtin_amdgcn_mfma_f32_16x16x32_bf16(al[i], bh[j], acc[i][j], 0, 0, 0);
                acc[i][j] = __builtin_amdgcn_mfma_f32_16x16x32_bf16(ah[i], bh[j], acc[i][j], 0, 0, 0);
            }
    }
    __syncthreads();   // all L1 reads done before overwrite
#pragma unroll
    for (int i = 0; i < 4; i++)
#pragma unroll
        for (int j = 0; j < 4; j++) {
            int col = cw + j*16 + l15;
            float bv = b1[col];
#pragma unroll
            for (int r = 0; r < 4; r++) {
                int row = i*16 + grp*4 + r;
                h_pk[row * AS + col] = packhl(lrelu(acc[i][j][r] + bv, 0.01f));
            }
        }
    __syncthreads();

    // ---- layer 2: K=256 ----
#pragma unroll
    for (int i = 0; i < 4; i++)
#pragma unroll
        for (int j = 0; j < 4; j++) acc[i][j] = (f32x4){0.f,0.f,0.f,0.f};
#pragma unroll
    for (int ks = 0; ks < 8; ks++) {
        bf16x8 ah[4], al[4], bh[4], bl[4];
#pragma unroll
        for (int i = 0; i < 4; i++) {
            unsigned q[8];
            const unsigned* p = h_pk + (i*16 + l15) * AS + ks*32 + grp*8;
            *(uint4v*)q     = *(const uint4v*)p;
            *(uint4v*)(q+4) = *(const uint4v*)(p + 4);
            unpack8(q, ah[i], al[i]);
        }
#pragma unroll
        for (int j = 0; j < 4; j++) {
            const size_t bo = (size_t)(cw + j*16 + l15) * 256 + ks*32 + grp*8;
            bh[j] = *(const bf16x8*)(w2h + bo);
            bl[j] = *(const bf16x8*)(w2l + bo);
        }
#pragma unroll
        for (int i = 0; i < 4; i++)
#pragma unroll
            for (int j = 0; j < 4; j++) {
                acc[i][j] = __builtin_amdgcn_mfma_f32_16x16x32_bf16(ah[i], bl[j], acc[i][j], 0, 0, 0);
                acc[i][j] = __builtin_amdgcn_mfma_f32_16x16x32_bf16(al[i], bh[j], acc[i][j], 0, 0, 0);
                acc[i][j] = __builtin_amdgcn_mfma_f32_16x16x32_bf16(ah[i], bh[j], acc[i][j], 0, 0, 0);
            }
    }
    __syncthreads();
#pragma unroll
    for (int i = 0; i < 4; i++)
#pragma unroll
        for (int j = 0; j < 4; j++) {
            int col = cw + j*16 + l15;
            float bv = b2[col];
#pragma unroll
            for (int r = 0; r < 4; r++) {
                int row = i*16 + grp*4 + r;
                h_pk[row * AS + col] = packhl(lrelu(acc[i][j][r] + bv, 0.01f));
            }
        }
    __syncthreads();

    // ---- layer 3: K=256 -> 24 cols; wave wv owns rows wv*16..+15 ----
    f32x4 acc3[2] = {(f32x4){0.f,0.f,0.f,0.f}, (f32x4){0.f,0.f,0.f,0.f}};
#pragma unroll
    for (int ks = 0; ks < 8; ks++) {
        unsigned q[8];
        const unsigned* p = h_pk + (wv*16 + l15) * AS + ks*32 + grp*8;
        *(uint4v*)q     = *(const uint4v*)p;
        *(uint4v*)(q+4) = *(const uint4v*)(p + 4);
        bf16x8 ah, al;
        unpack8(q, ah, al);
#pragma unroll
        for (int j = 0; j < 2; j++) {
            const size_t bo = (size_t)(j*16 + l15) * 256 + ks*32 + grp*8;
            bf16x8 bh = *(const bf16x8*)(w3h + bo);
            bf16x8 bl = *(const bf16x8*)(w3l + bo);
            acc3[j] = __builtin_amdgcn_mfma_f32_16x16x32_bf16(ah, bl, acc3[j], 0, 0, 0);
            acc3[j] = __builtin_amdgcn_mfma_f32_16x16x32_bf16(al, bh, acc3[j], 0, 0, 0);
            acc3[j] = __builtin_amdgcn_mfma_f32_16x16x32_bf16(ah, bh, acc3[j], 0, 0, 0);
        }
    }
    __syncthreads();   // all L3 reads done; reuse LDS as f32 out-stage
    float* ldsf = (float*)h_pk;   // [64][25]
#pragma unroll
    for (int j = 0; j < 2; j++)
#pragma unroll
        for (int r = 0; r < 4; r++) {
            int cl = j*16 + l15;
            if (cl < 24) {
                int rl = wv*16 + grp*4 + r;
                ldsf[rl * 25 + cl] = lrelu(acc3[j][r] + b3[cl], 0.01f);
            }
        }
    __syncthreads();
    int n = t & 63, c0 = t >> 6;
    int gr = r0 + n;
    if (gr < N_NODES)
        for (int c = c0; c < 24; c += 4)
            XtOut[(long)c * N_NODES + gr] = ldsf[n * 25 + c];
}

// ---------------- BN stats over channel-major layout (initial C0 channels) -------
__global__ void bn_stats_t(const float* __restrict__ Xt,
                           float* __restrict__ gsum, float* __restrict__ gsq)
{
    int ch = blockIdx.x, part = blockIdx.y, t = threadIdx.x;
    const float* p = Xt + (long)ch * N_NODES;
    float s = 0.f, q = 0.f;
    for (long i = (long)part * 25000 + t * 4; i < (long)(part + 1) * 25000; i += 1024) {
        float4 v = *(const float4*)(p + i);
        s += v.x + v.y + v.z + v.w;
        q += v.x*v.x + v.y*v.y + v.z*v.z + v.w*v.w;
    }
#pragma unroll
    for (int m = 1; m < 64; m <<= 1) {
        s += __shfl_xor(s, m, 64);
        q += __shfl_xor(q, m, 64);
    }
    __shared__ float ls[4], lq[4];
    int wid = t >> 6;
    if ((t & 63) == 0) { ls[wid] = s; lq[wid] = q; }
    __syncthreads();
    if (t == 0) {
        atomicAdd(gsum + ch, ls[0] + ls[1] + ls[2] + ls[3]);
        atomicAdd(gsq  + ch, lq[0] + lq[1] + lq[2] + lq[3]);
    }
}

// ---------------- densenet layer (round-12 config: 256 thr, 1 node/thread) ----------
__global__ __launch_bounds__(256) void dense_conv2(
    float* __restrict__ Xt, int C, int C0, int layerIdx,
    const float* __restrict__ W, int WS,
    const float* __restrict__ gamma, const float* __restrict__ beta,
    const float* __restrict__ gsum, const float* __restrict__ gsq,
    float* __restrict__ psq)
{
    constexpr int QOFF = 6 * 12 * NB;
    __shared__ float w_lds[132 * 12];       // [c][g], 48B rows (16B aligned)
    __shared__ float a_lds[132], b_lds[132];
    __shared__ float red[2][4][12];
    const int t = threadIdx.x;
    const int wid = t >> 6, lane = t & 63;

    for (int c = t; c < C0; c += 256) {
        float s = gsum[c], q = gsq[c];
        float mu  = s * (1.f / N_NODES);
        float var = q * (1.f / N_NODES) - mu * mu;
        float A = rsqrtf(var + 1e-5f) * gamma[c];
        a_lds[c] = A;
        b_lds[c] = beta[c] - mu * A;
    }
    for (int gc = wid; gc < C - C0; gc += 4) {
        const float* pp = psq + (size_t)gc * NB;
        const float* qq = psq + QOFF + (size_t)gc * NB;
        float s = 0.f, q = 0.f;
        for (int b = lane; b < NB; b += 64) { s += pp[b]; q += qq[b]; }
#pragma unroll
        for (int o = 1; o < 64; o <<= 1) {
            s += __shfl_xor(s, o, 64);
            q += __shfl_xor(q, o, 64);
        }
        if (lane == 0) {
            int c = C0 + gc;
            float mu  = s * (1.f / N_NODES);
            float var = q * (1.f / N_NODES) - mu * mu;
            float A = rsqrtf(var + 1e-5f) * gamma[c];
            a_lds[c] = A;
            b_lds[c] = beta[c] - mu * A;
        }
    }
    for (int i = t; i < 12 * C; i += 256) {
        int g = i / C, c = i - g * C;
        w_lds[c * 12 + g] = W[g * WS + c];   // transposed
    }
    __syncthreads();

    long n = (long)blockIdx.x * 256 + t;
    bool valid = (n < N_NODES);
    const float* xp = Xt + (valid ? n : 0);
    float acc[12];
#pragma unroll
    for (int g = 0; g < 12; g++) acc[g] = 0.f;

    float v[12], vn[12];
#pragma unroll
    for (int j = 0; j < 12; j++) v[j] = xp[(long)j * N_NODES];
    for (int c0 = 0; c0 < C; c0 += 12) {
        if (c0 + 12 < C) {
#pragma unroll
            for (int j = 0; j < 12; j++)
                vn[j] = xp[(long)(c0 + 12 + j) * N_NODES];
        }
#pragma unroll
        for (int j = 0; j < 12; j++) {
            int ch = c0 + j;
            float u = a_lds[ch] * v[j] + b_lds[ch];
            u = (u >= 0.f) ? u : 0.01f * u;
            const float4* wp = (const float4*)(w_lds + ch * 12);
            float4 w0 = wp[0], w1 = wp[1], w2 = wp[2];
            acc[0]  += u * w0.x; acc[1]  += u * w0.y; acc[2]  += u * w0.z; acc[3]  += u * w0.w;
            acc[4]  += u * w1.x; acc[5]  += u * w1.y; acc[6]  += u * w1.z; acc[7]  += u * w1.w;
            acc[8]  += u * w2.x; acc[9]  += u * w2.y; acc[10] += u * w2.z; acc[11] += u * w2.w;
        }
#pragma unroll
        for (int j = 0; j < 12; j++) v[j] = vn[j];
    }
    if (valid) {
#pragma unroll
        for (int g = 0; g < 12; g++)
            Xt[(long)(C + g) * N_NODES + n] = acc[g];
    }

    if (layerIdx < 5) {
        float sv[12], qv[12];
#pragma unroll
        for (int g = 0; g < 12; g++) {
            float a = valid ? acc[g] : 0.f;
            sv[g] = a; qv[g] = a * a;
        }
#pragma unroll
        for (int m = 1; m < 64; m <<= 1)
#pragma unroll
            for (int g = 0; g < 12; g++) {
                sv[g] += __shfl_xor(sv[g], m, 64);
                qv[g] += __shfl_xor(qv[g], m, 64);
            }
        if (lane == 0) {
#pragma unroll
            for (int g = 0; g < 12; g++) { red[0][wid][g] = sv[g]; red[1][wid][g] = qv[g]; }
        }
        __syncthreads();
        if (t < 12) {
            float s = red[0][0][t] + red[0][1][t] + red[0][2][t] + red[0][3][t];
            float q = red[1][0][t] + red[1][1][t] + red[1][2][t] + red[1][3][t];
            psq[((size_t)layerIdx * 12 + t) * NB + blockIdx.x] = s;
            psq[QOFF + ((size_t)layerIdx * 12 + t) * NB + blockIdx.x] = q;
        }
    }
}

// ---------------- GAT GEMM (f32-exact) + fused scores + bf16 H (stride 64) -------
template<int F>
__global__ __launch_bounds__(256) void gat_gemm(
    const float* __restrict__ A, const float* __restrict__ B,
    const float* __restrict__ avec, int K,
    unsigned short* __restrict__ Hb, float* __restrict__ sd, float* __restrict__ ss)
{
    __shared__ float At[16 * 68];
    __shared__ float Bt[16 * 64];
    __shared__ float ad[64], as_[64];
    const int t  = threadIdx.x;
    const int r0 = blockIdx.x * 64;
    const int tx = t & 15, ty = t >> 4;
    if (t < 64) {
        ad[t]  = (t < F) ? avec[t]     : 0.f;
        as_[t] = (t < F) ? avec[F + t] : 0.f;
    }

    float acc[4][4];
#pragma unroll
    for (int i = 0; i < 4; i++)
#pragma unroll
        for (int j = 0; j < 4; j++) acc[i][j] = 0.f;

    for (int k0 = 0; k0 < K; k0 += 16) {
        {
            int kk = t >> 4, rq = t & 15;
            float4 v = make_float4(0.f,0.f,0.f,0.f);
            if (k0 + kk < K)
                v = *(const float4*)(A + (long)(k0 + kk) * N_NODES + r0 + rq * 4);
            *(float4*)(At + kk * 68 + rq * 4) = v;
        }
        for (int i = t; i < 16 * 64; i += 256) {
            int kk = i >> 6, mq = i & 63;
            float v = 0.f;
            if (k0 + kk < K && mq < F) v = B[(long)(k0 + kk) * F + mq];
            Bt[kk * 64 + mq] = v;
        }
        __syncthreads();
#pragma unroll
        for (int kk = 0; kk < 16; kk++) {
            float4 av = *(const float4*)(At + kk * 68 + ty * 4);
            float4 bv = *(const float4*)(Bt + kk * 64 + tx * 4);
            float a_[4] = {av.x, av.y, av.z, av.w};
            float b_[4] = {bv.x, bv.y, bv.z, bv.w};
#pragma unroll
            for (int i = 0; i < 4; i++)
#pragma unroll
                for (int j = 0; j < 4; j++)
                    acc[i][j] += a_[i] * b_[j];
        }
        __syncthreads();
    }

#pragma unroll
    for (int i = 0; i < 4; i++) {
        int row = r0 + ty * 4 + i;
        float pd = 0.f, pq_ = 0.f;
#pragma unroll
        for (int j = 0; j < 4; j++) {
            int col = tx * 4 + j;
            pd  += acc[i][j] * ad[col];
            pq_ += acc[i][j] * as_[col];
        }
#pragma unroll
        for (int m = 1; m < 16; m <<= 1) {
            pd  += __shfl_xor(pd,  m, 64);
            pq_ += __shfl_xor(pq_, m, 64);
        }
        if (row < N_NODES) {
            if (tx == 0) { sd[row] = pd; ss[row] = pq_; }
            if (tx * 4 < F) {
                ushort4_t u;
#pragma unroll
                for (int j = 0; j < 4; j++) u[j] = f2bf(acc[i][j]);
                *(ushort4_t*)(Hb + (long)row * 64 + tx * 4) = u;
            }
        }
    }
}

// ---------------- fused GAT softmax+aggregate over CSR (4x-unrolled gather) -------
template<int F>
__global__ __launch_bounds__(256) void gat_aggregate2(
    const int* __restrict__ rstart, const int* __restrict__ csr_src,
    const float* __restrict__ sd, const float* __restrict__ ss,
    const unsigned short* __restrict__ Hb,
    const float* __restrict__ bias, float* __restrict__ outT)
{
    __shared__ float tile[64 * (F + 1)];
    const int t = threadIdx.x;
    const int wid = t >> 6, lane = t & 63;
    const long n0 = (long)blockIdx.x * 64;

#pragma unroll 1
    for (int k = 0; k < 16; k++) {
        long node = n0 + wid * 16 + k;
        float res = 0.f;
        if (node < N_NODES) {
            int st = rstart[node], en = rstart[node + 1];
            int deg = en - st;
            float sdn = sd[node];
            float acc = 0.f, dsum = 0.f;
            if (deg <= 64) {
                int sj = 0; float v = -3.4e38f;
                if (lane < deg) {
                    sj = csr_src[st + lane];
                    v = lrelu(sdn + ss[sj], 0.2f);
                }
                float m = v;
#pragma unroll
                for (int o = 1; o < 64; o <<= 1) m = fmaxf(m, __shfl_xor(m, o, 64));
                float p = (lane < deg) ? __expf(v - m) : 0.f;
                dsum = p;
                int j = 0;
                for (; j + 4 <= deg; j += 4) {
                    float a0 = __shfl(p, j, 64),   a1 = __shfl(p, j+1, 64);
                    float a2 = __shfl(p, j+2, 64), a3 = __shfl(p, j+3, 64);
                    int   s0 = __shfl(sj, j, 64),   s1 = __shfl(sj, j+1, 64);
                    int   s2 = __shfl(sj, j+2, 64), s3 = __shfl(sj, j+3, 64);
                    if (lane < F) {
                        float h0 = bf2f(Hb[(long)s0 * 64 + lane]);
                        float h1 = bf2f(Hb[(long)s1 * 64 + lane]);
                        float h2 = bf2f(Hb[(long)s2 * 64 + lane]);
                        float h3 = bf2f(Hb[(long)s3 * 64 + lane]);
                        acc += a0 * h0; acc += a1 * h1; acc += a2 * h2; acc += a3 * h3;
                    }
                }
                for (; j < deg; j++) {
                    float a = __shfl(p, j, 64);
                    int   s = __shfl(sj, j, 64);
                    if (lane < F) acc += a * bf2f(Hb[(long)s * 64 + lane]);
                }
            } else {
                float m = -3.4e38f;
                for (int base = st; base < en; base += 64) {
                    int cnt = min(64, en - base);
                    float v = -3.4e38f;
                    if (lane < cnt) {
                        int s = csr_src[base + lane];
                        v = lrelu(sdn + ss[s], 0.2f);
                    }
#pragma unroll
                    for (int o = 1; o < 64; o <<= 1) v = fmaxf(v, __shfl_xor(v, o, 64));
                    m = fmaxf(m, v);
                }
                for (int base = st; base < en; base += 64) {
                    int cnt = min(64, en - base);
                    float p = 0.f; int sj = 0;
                    if (lane < cnt) {
                        sj = csr_src[base + lane];
                        float v = lrelu(sdn + ss[sj], 0.2f);
                        p = __expf(v - m);
                    }
                    dsum += p;
                    int j = 0;
                    for (; j + 4 <= cnt; j += 4) {
                        float a0 = __shfl(p, j, 64),   a1 = __shfl(p, j+1, 64);
                        float a2 = __shfl(p, j+2, 64), a3 = __shfl(p, j+3, 64);
                        int   s0 = __shfl(sj, j, 64),   s1 = __shfl(sj, j+1, 64);
                        int   s2 = __shfl(sj, j+2, 64), s3 = __shfl(sj, j+3, 64);
                        if (lane < F) {
                            float h0 = bf2f(Hb[(long)s0 * 64 + lane]);
                            float h1 = bf2f(Hb[(long)s1 * 64 + lane]);
                            float h2 = bf2f(Hb[(long)s2 * 64 + lane]);
                            float h3 = bf2f(Hb[(long)s3 * 64 + lane]);
                            acc += a0 * h0; acc += a1 * h1; acc += a2 * h2; acc += a3 * h3;
                        }
                    }
                    for (; j < cnt; j++) {
                        float a = __shfl(p, j, 64);
                        int   s = __shfl(sj, j, 64);
                        if (lane < F) acc += a * bf2f(Hb[(long)s * 64 + lane]);
                    }
                }
            }
#pragma unroll
            for (int o = 1; o < 64; o <<= 1) dsum += __shfl_xor(dsum, o, 64);
            res = acc / (dsum + 1e-16f);
        }
        if (lane < F) tile[(wid * 16 + k) * (F + 1) + lane] = res + bias[lane];
    }
    __syncthreads();
    for (int idx = t; idx < F * 64; idx += 256) {
        int c = idx / 64, i = idx % 64;
        long n = n0 + i;
        if (n < N_NODES) outT[(long)c * N_NODES + n] = tile[i * (F + 1) + c];
    }
}

// ---------------- final transpose [132][N] -> [N,132] ----------------
__global__ __launch_bounds__(256) void transpose_out(const float* __restrict__ Xt,
                                                     float* __restrict__ out)
{
    __shared__ float tile[64 * 133];
    int t = threadIdx.x;
    long n0 = (long)blockIdx.x * 64;
    int lane = t & 63, cq = t >> 6;
    for (int c = cq; c < 132; c += 4) {
        long n = n0 + lane;
        float v = (n < N_NODES) ? Xt[(long)c * N_NODES + n] : 0.f;
        tile[lane * 133 + c] = v;
    }
    __syncthreads();
    for (int idx = t; idx < 64 * 132; idx += 256) {
        int r = idx / 132, c = idx % 132;
        long n = n0 + r;
        if (n < N_NODES) out[n * 132 + c] = tile[r * 133 + c];
    }
}

// ---------------- bucket-sorted CSR build ----------------
__global__ __launch_bounds__(256) void bkt_hist(const int* __restrict__ dst,
                                                int* __restrict__ bcnt)
{
    __shared__ int lh[NBKT];
    for (int i = threadIdx.x; i < NBKT; i += 256) lh[i] = 0;
    __syncthreads();
    for (long e = (long)blockIdx.x * 256 + threadIdx.x; e < N_EDGES; e += (long)gridDim.x * 256)
        atomicAdd(&lh[dst[e] >> 8], 1);
    __syncthreads();
    for (int i = threadIdx.x; i < NBKT; i += 256)
        if (lh[i]) atomicAdd(&bcnt[i * 16], lh[i]);
}

__global__ void bkt_scan(const int* __restrict__ bcnt, int* __restrict__ boff,
                         int* __restrict__ bcur, int* __restrict__ rstart)
{
    __shared__ int ls[512];
    int t = threadIdx.x;
    int v = (t < NBKT) ? bcnt[t * 16] : 0;
    ls[t] = v; __syncthreads();
    for (int o = 1; o < 512; o <<= 1) {
        int y = (t >= o) ? ls[t - o] : 0;
        __syncthreads();
        ls[t] += y;
        __syncthreads();
    }
    if (t < NBKT) { int ex = ls[t] - v; boff[t] = ex; bcur[t * 16] = ex; }
    if (t == 0) { boff[NBKT] = N_EDGES; rstart[N_NODES] = N_EDGES; }
}

__global__ void bkt_scatter(const int* __restrict__ src, const int* __restrict__ dst,
                            int* __restrict__ bcur, int2* __restrict__ pairs)
{
    for (long e = (long)blockIdx.x * 256 + threadIdx.x; e < N_EDGES; e += (long)gridDim.x * 256) {
        int d = dst[e];
        int pos = atomicAdd(&bcur[(d >> 8) * 16], 1);
        pairs[pos] = make_int2(d, src[e]);
    }
}

__global__ __launch_bounds__(256) void bkt_build(const int2* __restrict__ pairs,
                                                 const int* __restrict__ boff,
                                                 int* __restrict__ rstart,
                                                 int* __restrict__ csr_src)
{
    __shared__ int lh[256], sc[256], lbase[256], lcur[256];
    int b = blockIdx.x, t = threadIdx.x;
    int st = boff[b], en = boff[b + 1];
    lh[t] = 0;
    __syncthreads();
    for (int i = st + t; i < en; i += 256)
        atomicAdd(&lh[pairs[i].x & 255], 1);
    __syncthreads();
    int v = lh[t];
    sc[t] = v; __syncthreads();
    for (int o = 1; o < 256; o <<= 1) {
        int y = (t >= o) ? sc[t - o] : 0;
        __syncthreads();
        sc[t] += y;
        __syncthreads();
    }
    int ex = sc[t] - v;
    lbase[t] = st + ex;
    lcur[t] = 0;
    int node = (b << 8) + t;
    if (node < N_NODES) rstart[node] = st + ex;
    __syncthreads();
    for (int i = st + t; i < en; i += 256) {
        int2 p = pairs[i];
        int ld = p.x & 255;
        int pos = lbase[ld] + atomicAdd(&lcur[ld], 1);
        csr_src[pos] = p.y;
    }
}

// ---------------- host helpers ----------------
static void run_dense_block_t(hipStream_t stream, float* Xt, int C0,
                              const float* convW, int WS,
                              const float* gamma, const float* beta,
                              float* gsum, float* gsq, float* psq)
{
    hipMemsetAsync(gsum, 0, 264 * sizeof(float), stream);
    bn_stats_t<<<dim3(C0, 4), 256, 0, stream>>>(Xt, gsum, gsq);
    for (int i = 0; i < 6; i++) {
        int C = C0 + 12 * i;
        dense_conv2<<<NB, 256, 0, stream>>>(Xt, C, C0, i, convW + (size_t)i * 12 * WS, WS,
                                            gamma + (size_t)i * WS, beta + (size_t)i * WS,
                                            gsum, gsq, psq);
    }
}

template<int F>
static void run_gat(hipStream_t stream, const float* XtIn, int K,
                    const float* W, const float* avec, const float* bias,
                    unsigned short* Hb, float* outT,
                    float* sd, float* ss, const int* rstart, const int* csr_src)
{
    gat_gemm<F><<<GG, 256, 0, stream>>>(XtIn, W, avec, K, Hb, sd, ss);
    gat_aggregate2<F><<<GG, 256, 0, stream>>>(rstart, csr_src, sd, ss, Hb, bias, outT);
}

extern "C" void kernel_launch(void* const* d_in, const int* in_sizes, int n_in,
                              void* d_out, int out_size, void* d_ws, size_t ws_size,
                              hipStream_t stream)
{
    const float* x     = (const float*)d_in[0];
    const int*   src   = (const int*)d_in[1];
    const int*   dst   = (const int*)d_in[2];
    const float* w1    = (const float*)d_in[3];
    const float* b1    = (const float*)d_in[4];
    const float* w2    = (const float*)d_in[5];
    const float* b2    = (const float*)d_in[6];
    const float* w3    = (const float*)d_in[7];
    const float* b3    = (const float*)d_in[8];
    const float* conv1 = (const float*)d_in[9];
    const float* bn1g  = (const float*)d_in[10];
    const float* bn1b  = (const float*)d_in[11];
    const float* g1w   = (const float*)d_in[12];
    const float* g1a   = (const float*)d_in[13];
    const float* g1b   = (const float*)d_in[14];
    const float* conv2 = (const float*)d_in[15];
    const float* bn2g  = (const float*)d_in[16];
    const float* bn2b  = (const float*)d_in[17];
    const float* g2w   = (const float*)d_in[18];
    const float* g2a   = (const float*)d_in[19];
    const float* g2b   = (const float*)d_in[20];
    const float* conv3 = (const float*)d_in[21];
    const float* bn3g  = (const float*)d_in[22];
    const float* bn3b  = (const float*)d_in[23];
    float* out = (float*)d_out;

    char* ws = (char*)d_ws;
    size_t off = 0;
    auto alloc = [&](size_t bytes) -> void* {
        void* p = ws + off;
        off += (bytes + 255) & ~(size_t)255;
        return p;
    };
    float*    h      = (float*)alloc((size_t)N_NODES * 256 * 4); // overlays: Hb + Xt3
    float*    Xt1    = (float*)alloc((size_t)96  * N_NODES * 4);
    float*    Xt2    = (float*)alloc((size_t)120 * N_NODES * 4);
    int*      csr_src= (int*)alloc((size_t)N_EDGES * 4);
    int2*     pairs  = (int2*)alloc((size_t)N_EDGES * 8);
    int*      rstart = (int*)alloc((size_t)(N_NODES + 1) * 4);
    int*      bcnt   = (int*)alloc((size_t)NBKT * 16 * 4);
    int*      bcur   = (int*)alloc((size_t)NBKT * 16 * 4);
    int*      boff   = (int*)alloc((size_t)(NBKT + 1) * 4);
    float*    sd     = (float*)alloc((size_t)N_NODES * 4);
    float*    ss     = (float*)alloc((size_t)N_NODES * 4);
    float*    gsum   = (float*)alloc(264 * 4);
    float*    gsq    = gsum + 132;
    float*    psq    = (float*)alloc((size_t)2 * 6 * 12 * NB * 4);
    unsigned short* wt1h = (unsigned short*)alloc(256 * 64  * 2);
    unsigned short* wt1l = (unsigned short*)alloc(256 * 64  * 2);
    unsigned short* wt2h = (unsigned short*)alloc(256 * 256 * 2);
    unsigned short* wt2l = (unsigned short*)alloc(256 * 256 * 2);
    unsigned short* wt3h = (unsigned short*)alloc(32  * 256 * 2);
    unsigned short* wt3l = (unsigned short*)alloc(32  * 256 * 2);

    // overlays in h (102.4 MB):
    unsigned short* Hb  = (unsigned short*)h;            // [N][64] bf16 = 12.8 MB (128B rows)
    float* Xt3 = (float*)((char*)h + (size_t)16 * 1024 * 1024); // [132][N] f32 = 52.8 MB

    // ---- bucket-sorted CSR by dst (shared by both GATs), payload = src values ----
    hipMemsetAsync(bcnt, 0, (size_t)NBKT * 16 * 4, stream);
    bkt_hist<<<512, 256, 0, stream>>>(dst, bcnt);
    bkt_scan<<<1, 512, 0, stream>>>(bcnt, boff, bcur, rstart);
    bkt_scatter<<<2048, 256, 0, stream>>>(src, dst, bcur, pairs);
    bkt_build<<<NBKT, 256, 0, stream>>>(pairs, boff, rstart, csr_src);

    // ---- weight prep (f32 -> transposed hi/lo bf16) ----
    cvt_wT_split<<<(256 * 64  + 255) / 256, 256, 0, stream>>>(w1, wt1h, wt1l, 64,  256, 256);
    cvt_wT_split<<<(256 * 256 + 255) / 256, 256, 0, stream>>>(w2, wt2h, wt2l, 256, 256, 256);
    cvt_wT_split<<<(32  * 256 + 255) / 256, 256, 0, stream>>>(w3, wt3h, wt3l, 256, 24,  32);

    // ---- fully-fused MLP (x -> L1 -> L2 -> L3 -> Xt1, activations stay in LDS) ----
    mlp_fused<<<GG, 256, 0, stream>>>(x, wt1h, wt1l, b1, wt2h, wt2l, b2,
                                      wt3h, wt3l, b3, Xt1);

    // ---- dense block 1 (24 -> 96, channel-major) ----
    run_dense_block_t(stream, Xt1, 24, conv1, 84, bn1g, bn1b, gsum, gsq, psq);

    // ---- GAT 1 (96 -> 48), output transposed into Xt2 rows 0..47 ----
    run_gat<48>(stream, Xt1, 96, g1w, g1a, g1b, Hb, Xt2, sd, ss, rstart, csr_src);

    // ---- dense block 2 (48 -> 120) ----
    run_dense_block_t(stream, Xt2, 48, conv2, 108, bn2g, bn2b, gsum, gsq, psq);

    // ---- GAT 2 (120 -> 60), output transposed into Xt3 rows 0..59 ----
    run_gat<60>(stream, Xt2, 120, g2w, g2a, g2b, Hb, Xt3, sd, ss, rstart, csr_src);

    // ---- dense block 3 (60 -> 132) ----
    run_dense_block_t(stream, Xt3, 60, conv3, 120, bn3g, bn3b, gsum, gsq, psq);

    // ---- final transpose to row-major d_out ----
    transpose_out<<<GG, 256, 0, stream>>>(Xt3, out);
}

// Round 16
// 987.346 us; speedup vs baseline: 1.3328x; 1.0508x over previous
//
#include <hip/hip_runtime.h>
#include <math.h>

#define N_NODES 100000
#define N_EDGES 1600000

static constexpr int GG = (N_NODES + 63) / 64;          // 1563
static constexpr int NB = (N_NODES + 255) / 256;        // 391 dense blocks
static constexpr int NBKT = (N_NODES + 255) / 256;      // 391 buckets (dst >> 8)
static constexpr int SCG = 512;                          // scatter grid
static constexpr int EPB = (N_EDGES + SCG - 1) / SCG;    // 3125 edges/block

typedef __attribute__((ext_vector_type(8))) short          bf16x8;
typedef __attribute__((ext_vector_type(8))) unsigned short ushort8_t;
typedef __attribute__((ext_vector_type(4))) unsigned short ushort4_t;
typedef __attribute__((ext_vector_type(4))) float          f32x4;
typedef __attribute__((ext_vector_type(4))) unsigned       uint4v;

__device__ __forceinline__ float lrelu(float v, float s){ return v >= 0.f ? v : v*s; }

__device__ __forceinline__ unsigned short f2bf(float f){
    unsigned u = __float_as_uint(f);
    unsigned r = (u + 0x7FFFu + ((u >> 16) & 1u)) >> 16;   // RNE
    return (unsigned short)r;
}
__device__ __forceinline__ float bf2f(unsigned short h){
    return __uint_as_float(((unsigned)h) << 16);
}
// packed hi|lo<<16 bf16 pair of an f32 (hi + lo represents f to ~2^-17 rel)
__device__ __forceinline__ unsigned packhl(float f){
    unsigned short hi = f2bf(f);
    unsigned short lo = f2bf(f - bf2f(hi));
    return (unsigned)hi | ((unsigned)lo << 16);
}
// 8 packed u32 -> hi-frag and lo-frag (bf16x8 each)
__device__ __forceinline__ void unpack8(const unsigned* q, bf16x8& ah, bf16x8& al){
    unsigned a32[4], l32[4];
#pragma unroll
    for (int k = 0; k < 4; k++) {
        a32[k] = (q[2*k] & 0xffffu) | (q[2*k+1] << 16);
        l32[k] = (q[2*k] >> 16)     | (q[2*k+1] & 0xffff0000u);
    }
    ah = *(const bf16x8*)a32;
    al = *(const bf16x8*)l32;
}

// ---------------- weight split: wt_hi/lo[n][k] = hi/lo bf16 of w[k][n] ----------------
__global__ void cvt_wT_split(const float* __restrict__ w,
                             unsigned short* __restrict__ whi,
                             unsigned short* __restrict__ wlo,
                             int K, int Nsrc, int Npad)
{
    int idx = blockIdx.x * 256 + threadIdx.x;
    if (idx >= Npad * K) return;
    int n = idx / K, k = idx % K;
    float v = (n < Nsrc) ? w[(long)k * Nsrc + n] : 0.f;
    unsigned short hi = f2bf(v);
    whi[idx] = hi;
    wlo[idx] = f2bf(v - bf2f(hi));
}

// ---------------- fully-fused MLP (round-11 config: 64 rows, packed hi/lo u32) --------
__global__ __launch_bounds__(256) void mlp_fused(
    const float* __restrict__ x,
    const unsigned short* __restrict__ w1h, const unsigned short* __restrict__ w1l,
    const float* __restrict__ b1,
    const unsigned short* __restrict__ w2h, const unsigned short* __restrict__ w2l,
    const float* __restrict__ b2,
    const unsigned short* __restrict__ w3h, const unsigned short* __restrict__ w3l,
    const float* __restrict__ b3,
    float* __restrict__ XtOut)
{
    constexpr int AS = 260;
    __shared__ unsigned h_pk[64 * AS];          // 66.6 KB
    const int t = threadIdx.x;
    const int r0 = blockIdx.x * 64;
    const int wv = t >> 6, lane = t & 63;
    const int l15 = lane & 15, grp = lane >> 4;
    const int cw = wv * 64;

    // ---- stage x (64 rows x 64 f32) as packed hi/lo ----
    {
        int c = t;
#pragma unroll
        for (int it = 0; it < 4; it++, c += 256) {   // 1024 float4 chunks
            int row = c >> 4, kq = c & 15;
            int gr = r0 + row;
            float4 v = make_float4(0.f, 0.f, 0.f, 0.f);
            if (gr < N_NODES) v = *(const float4*)(x + (long)gr * 64 + kq * 4);
            unsigned p[4] = {packhl(v.x), packhl(v.y), packhl(v.z), packhl(v.w)};
            *(uint4v*)(h_pk + row * AS + kq * 4) = *(const uint4v*)p;
        }
    }
    __syncthreads();

    f32x4 acc[4][4];

    // ---- layer 1: K=64 ----
#pragma unroll
    for (int i = 0; i < 4; i++)
#pragma unroll
        for (int j = 0; j < 4; j++) acc[i][j] = (f32x4){0.f,0.f,0.f,0.f};
#pragma unroll
    for (int ks = 0; ks < 2; ks++) {
        bf16x8 ah[4], al[4], bh[4], bl[4];
#pragma unroll
        for (int i = 0; i < 4; i++) {
            unsigned q[8];
            const unsigned* p = h_pk + (i*16 + l15) * AS + ks*32 + grp*8;
            *(uint4v*)q     = *(const uint4v*)p;
            *(uint4v*)(q+4) = *(const uint4v*)(p + 4);
            unpack8(q, ah[i], al[i]);
        }
#pragma unroll
        for (int j = 0; j < 4; j++) {
            const size_t bo = (size_t)(cw + j*16 + l15) * 64 + ks*32 + grp*8;
            bh[j] = *(const bf16x8*)(w1h + bo);
            bl[j] = *(const bf16x8*)(w1l + bo);
        }
#pragma unroll
        for (int i = 0; i < 4; i++)
#pragma unroll
            for (int j = 0; j < 4; j++) {
                acc[i][j] = __builtin_amdgcn_mfma_f32_16x16x32_bf16(ah[i], bl[j], acc[i][j], 0, 0, 0);
                acc[i][j] = __builtin_amdgcn_mfma_f32_16x16x32_bf16(al[i], bh[j], acc[i][j], 0, 0, 0);
                acc[i][j] = __builtin_amdgcn_mfma_f32_16x16x32_bf16(ah[i], bh[j], acc[i][j], 0, 0, 0);
            }
    }
    __syncthreads();   // all L1 reads done before overwrite
#pragma unroll
    for (int i = 0; i < 4; i++)
#pragma unroll
        for (int j = 0; j < 4; j++) {
            int col = cw + j*16 + l15;
            float bv = b1[col];
#pragma unroll
            for (int r = 0; r < 4; r++) {
                int row = i*16 + grp*4 + r;
                h_pk[row * AS + col] = packhl(lrelu(acc[i][j][r] + bv, 0.01f));
            }
        }
    __syncthreads();

    // ---- layer 2: K=256 ----
#pragma unroll
    for (int i = 0; i < 4; i++)
#pragma unroll
        for (int j = 0; j < 4; j++) acc[i][j] = (f32x4){0.f,0.f,0.f,0.f};
#pragma unroll
    for (int ks = 0; ks < 8; ks++) {
        bf16x8 ah[4], al[4], bh[4], bl[4];
#pragma unroll
        for (int i = 0; i < 4; i++) {
            unsigned q[8];
            const unsigned* p = h_pk + (i*16 + l15) * AS + ks*32 + grp*8;
            *(uint4v*)q     = *(const uint4v*)p;
            *(uint4v*)(q+4) = *(const uint4v*)(p + 4);
            unpack8(q, ah[i], al[i]);
        }
#pragma unroll
        for (int j = 0; j < 4; j++) {
            const size_t bo = (size_t)(cw + j*16 + l15) * 256 + ks*32 + grp*8;
            bh[j] = *(const bf16x8*)(w2h + bo);
            bl[j] = *(const bf16x8*)(w2l + bo);
        }
#pragma unroll
        for (int i = 0; i < 4; i++)
#pragma unroll
            for (int j = 0; j < 4; j++) {
                acc[i][j] = __builtin_amdgcn_mfma_f32_16x16x32_bf16(ah[i], bl[j], acc[i][j], 0, 0, 0);
                acc[i][j] = __builtin_amdgcn_mfma_f32_16x16x32_bf16(al[i], bh[j], acc[i][j], 0, 0, 0);
                acc[i][j] = __builtin_amdgcn_mfma_f32_16x16x32_bf16(ah[i], bh[j], acc[i][j], 0, 0, 0);
            }
    }
    __syncthreads();
#pragma unroll
    for (int i = 0; i < 4; i++)
#pragma unroll
        for (int j = 0; j < 4; j++) {
            int col = cw + j*16 + l15;
            float bv = b2[col];
#pragma unroll
            for (int r = 0; r < 4; r++) {
                int row = i*16 + grp*4 + r;
                h_pk[row * AS + col] = packhl(lrelu(acc[i][j][r] + bv, 0.01f));
            }
        }
    __syncthreads();

    // ---- layer 3: K=256 -> 24 cols; wave wv owns rows wv*16..+15 ----
    f32x4 acc3[2] = {(f32x4){0.f,0.f,0.f,0.f}, (f32x4){0.f,0.f,0.f,0.f}};
#pragma unroll
    for (int ks = 0; ks < 8; ks++) {
        unsigned q[8];
        const unsigned* p = h_pk + (wv*16 + l15) * AS + ks*32 + grp*8;
        *(uint4v*)q     = *(const uint4v*)p;
        *(uint4v*)(q+4) = *(const uint4v*)(p + 4);
        bf16x8 ah, al;
        unpack8(q, ah, al);
#pragma unroll
        for (int j = 0; j < 2; j++) {
            const size_t bo = (size_t)(j*16 + l15) * 256 + ks*32 + grp*8;
            bf16x8 bh = *(const bf16x8*)(w3h + bo);
            bf16x8 bl = *(const bf16x8*)(w3l + bo);
            acc3[j] = __builtin_amdgcn_mfma_f32_16x16x32_bf16(ah, bl, acc3[j], 0, 0, 0);
            acc3[j] = __builtin_amdgcn_mfma_f32_16x16x32_bf16(al, bh, acc3[j], 0, 0, 0);
            acc3[j] = __builtin_amdgcn_mfma_f32_16x16x32_bf16(ah, bh, acc3[j], 0, 0, 0);
        }
    }
    __syncthreads();   // all L3 reads done; reuse LDS as f32 out-stage
    float* ldsf = (float*)h_pk;   // [64][25]
#pragma unroll
    for (int j = 0; j < 2; j++)
#pragma unroll
        for (int r = 0; r < 4; r++) {
            int cl = j*16 + l15;
            if (cl < 24) {
                int rl = wv*16 + grp*4 + r;
                ldsf[rl * 25 + cl] = lrelu(acc3[j][r] + b3[cl], 0.01f);
            }
        }
    __syncthreads();
    int n = t & 63, c0 = t >> 6;
    int gr = r0 + n;
    if (gr < N_NODES)
        for (int c = c0; c < 24; c += 4)
            XtOut[(long)c * N_NODES + gr] = ldsf[n * 25 + c];
}

// ---------------- BN stats over channel-major layout (initial C0 channels) -------
__global__ void bn_stats_t(const float* __restrict__ Xt,
                           float* __restrict__ gsum, float* __restrict__ gsq)
{
    int ch = blockIdx.x, part = blockIdx.y, t = threadIdx.x;
    const float* p = Xt + (long)ch * N_NODES;
    float s = 0.f, q = 0.f;
    for (long i = (long)part * 25000 + t * 4; i < (long)(part + 1) * 25000; i += 1024) {
        float4 v = *(const float4*)(p + i);
        s += v.x + v.y + v.z + v.w;
        q += v.x*v.x + v.y*v.y + v.z*v.z + v.w*v.w;
    }
#pragma unroll
    for (int m = 1; m < 64; m <<= 1) {
        s += __shfl_xor(s, m, 64);
        q += __shfl_xor(q, m, 64);
    }
    __shared__ float ls[4], lq[4];
    int wid = t >> 6;
    if ((t & 63) == 0) { ls[wid] = s; lq[wid] = q; }
    __syncthreads();
    if (t == 0) {
        atomicAdd(gsum + ch, ls[0] + ls[1] + ls[2] + ls[3]);
        atomicAdd(gsq  + ch, lq[0] + lq[1] + lq[2] + lq[3]);
    }
}

// ---------------- densenet layer (256 thr, 1 node/thread, vectorized W) ----------
__global__ __launch_bounds__(256) void dense_conv2(
    float* __restrict__ Xt, int C, int C0, int layerIdx,
    const float* __restrict__ W, int WS,
    const float* __restrict__ gamma, const float* __restrict__ beta,
    const float* __restrict__ gsum, const float* __restrict__ gsq,
    float* __restrict__ psq)
{
    constexpr int QOFF = 6 * 12 * NB;
    __shared__ float w_lds[132 * 12];       // [c][g], 48B rows (16B aligned)
    __shared__ float a_lds[132], b_lds[132];
    __shared__ float red[2][4][12];
    const int t = threadIdx.x;
    const int wid = t >> 6, lane = t & 63;

    for (int c = t; c < C0; c += 256) {
        float s = gsum[c], q = gsq[c];
        float mu  = s * (1.f / N_NODES);
        float var = q * (1.f / N_NODES) - mu * mu;
        float A = rsqrtf(var + 1e-5f) * gamma[c];
        a_lds[c] = A;
        b_lds[c] = beta[c] - mu * A;
    }
    for (int gc = wid; gc < C - C0; gc += 4) {
        const float* pp = psq + (size_t)gc * NB;
        const float* qq = psq + QOFF + (size_t)gc * NB;
        float s = 0.f, q = 0.f;
        for (int b = lane; b < NB; b += 64) { s += pp[b]; q += qq[b]; }
#pragma unroll
        for (int o = 1; o < 64; o <<= 1) {
            s += __shfl_xor(s, o, 64);
            q += __shfl_xor(q, o, 64);
        }
        if (lane == 0) {
            int c = C0 + gc;
            float mu  = s * (1.f / N_NODES);
            float var = q * (1.f / N_NODES) - mu * mu;
            float A = rsqrtf(var + 1e-5f) * gamma[c];
            a_lds[c] = A;
            b_lds[c] = beta[c] - mu * A;
        }
    }
    for (int i = t; i < 12 * C; i += 256) {
        int g = i / C, c = i - g * C;
        w_lds[c * 12 + g] = W[g * WS + c];   // transposed
    }
    __syncthreads();

    long n = (long)blockIdx.x * 256 + t;
    bool valid = (n < N_NODES);
    const float* xp = Xt + (valid ? n : 0);
    float acc[12];
#pragma unroll
    for (int g = 0; g < 12; g++) acc[g] = 0.f;

    float v[12], vn[12];
#pragma unroll
    for (int j = 0; j < 12; j++) v[j] = xp[(long)j * N_NODES];
    for (int c0 = 0; c0 < C; c0 += 12) {
        if (c0 + 12 < C) {
#pragma unroll
            for (int j = 0; j < 12; j++)
                vn[j] = xp[(long)(c0 + 12 + j) * N_NODES];
        }
#pragma unroll
        for (int j = 0; j < 12; j++) {
            int ch = c0 + j;
            float u = a_lds[ch] * v[j] + b_lds[ch];
            u = (u >= 0.f) ? u : 0.01f * u;
            const float4* wp = (const float4*)(w_lds + ch * 12);
            float4 w0 = wp[0], w1 = wp[1], w2 = wp[2];
            acc[0]  += u * w0.x; acc[1]  += u * w0.y; acc[2]  += u * w0.z; acc[3]  += u * w0.w;
            acc[4]  += u * w1.x; acc[5]  += u * w1.y; acc[6]  += u * w1.z; acc[7]  += u * w1.w;
            acc[8]  += u * w2.x; acc[9]  += u * w2.y; acc[10] += u * w2.z; acc[11] += u * w2.w;
        }
#pragma unroll
        for (int j = 0; j < 12; j++) v[j] = vn[j];
    }
    if (valid) {
#pragma unroll
        for (int g = 0; g < 12; g++)
            Xt[(long)(C + g) * N_NODES + n] = acc[g];
    }

    if (layerIdx < 5) {
        float sv[12], qv[12];
#pragma unroll
        for (int g = 0; g < 12; g++) {
            float a = valid ? acc[g] : 0.f;
            sv[g] = a; qv[g] = a * a;
        }
#pragma unroll
        for (int m = 1; m < 64; m <<= 1)
#pragma unroll
            for (int g = 0; g < 12; g++) {
                sv[g] += __shfl_xor(sv[g], m, 64);
                qv[g] += __shfl_xor(qv[g], m, 64);
            }
        if (lane == 0) {
#pragma unroll
            for (int g = 0; g < 12; g++) { red[0][wid][g] = sv[g]; red[1][wid][g] = qv[g]; }
        }
        __syncthreads();
        if (t < 12) {
            float s = red[0][0][t] + red[0][1][t] + red[0][2][t] + red[0][3][t];
            float q = red[1][0][t] + red[1][1][t] + red[1][2][t] + red[1][3][t];
            psq[((size_t)layerIdx * 12 + t) * NB + blockIdx.x] = s;
            psq[QOFF + ((size_t)layerIdx * 12 + t) * NB + blockIdx.x] = q;
        }
    }
}

// ---------------- GAT GEMM (f32-exact) + fused scores + bf16 H (stride 64) -------
template<int F>
__global__ __launch_bounds__(256) void gat_gemm(
    const float* __restrict__ A, const float* __restrict__ B,
    const float* __restrict__ avec, int K,
    unsigned short* __restrict__ Hb, float* __restrict__ sd, float* __restrict__ ss)
{
    __shared__ float At[16 * 68];
    __shared__ float Bt[16 * 64];
    __shared__ float ad[64], as_[64];
    const int t  = threadIdx.x;
    const int r0 = blockIdx.x * 64;
    const int tx = t & 15, ty = t >> 4;
    if (t < 64) {
        ad[t]  = (t < F) ? avec[t]     : 0.f;
        as_[t] = (t < F) ? avec[F + t] : 0.f;
    }

    float acc[4][4];
#pragma unroll
    for (int i = 0; i < 4; i++)
#pragma unroll
        for (int j = 0; j < 4; j++) acc[i][j] = 0.f;

    for (int k0 = 0; k0 < K; k0 += 16) {
        {
            int kk = t >> 4, rq = t & 15;
            float4 v = make_float4(0.f,0.f,0.f,0.f);
            if (k0 + kk < K)
                v = *(const float4*)(A + (long)(k0 + kk) * N_NODES + r0 + rq * 4);
            *(float4*)(At + kk * 68 + rq * 4) = v;
        }
        for (int i = t; i < 16 * 64; i += 256) {
            int kk = i >> 6, mq = i & 63;
            float v = 0.f;
            if (k0 + kk < K && mq < F) v = B[(long)(k0 + kk) * F + mq];
            Bt[kk * 64 + mq] = v;
        }
        __syncthreads();
#pragma unroll
        for (int kk = 0; kk < 16; kk++) {
            float4 av = *(const float4*)(At + kk * 68 + ty * 4);
            float4 bv = *(const float4*)(Bt + kk * 64 + tx * 4);
            float a_[4] = {av.x, av.y, av.z, av.w};
            float b_[4] = {bv.x, bv.y, bv.z, bv.w};
#pragma unroll
            for (int i = 0; i < 4; i++)
#pragma unroll
                for (int j = 0; j < 4; j++)
                    acc[i][j] += a_[i] * b_[j];
        }
        __syncthreads();
    }

#pragma unroll
    for (int i = 0; i < 4; i++) {
        int row = r0 + ty * 4 + i;
        float pd = 0.f, pq_ = 0.f;
#pragma unroll
        for (int j = 0; j < 4; j++) {
            int col = tx * 4 + j;
            pd  += acc[i][j] * ad[col];
            pq_ += acc[i][j] * as_[col];
        }
#pragma unroll
        for (int m = 1; m < 16; m <<= 1) {
            pd  += __shfl_xor(pd,  m, 64);
            pq_ += __shfl_xor(pq_, m, 64);
        }
        if (row < N_NODES) {
            if (tx == 0) { sd[row] = pd; ss[row] = pq_; }
            if (tx * 4 < F) {
                ushort4_t u;
#pragma unroll
                for (int j = 0; j < 4; j++) u[j] = f2bf(acc[i][j]);
                *(ushort4_t*)(Hb + (long)row * 64 + tx * 4) = u;
            }
        }
    }
}

// ---------------- fused GAT softmax+aggregate over CSR (4x-unrolled gather) -------
template<int F>
__global__ __launch_bounds__(256) void gat_aggregate2(
    const int* __restrict__ rstart, const int* __restrict__ csr_src,
    const float* __restrict__ sd, const float* __restrict__ ss,
    const unsigned short* __restrict__ Hb,
    const float* __restrict__ bias, float* __restrict__ outT)
{
    __shared__ float tile[64 * (F + 1)];
    const int t = threadIdx.x;
    const int wid = t >> 6, lane = t & 63;
    const long n0 = (long)blockIdx.x * 64;

#pragma unroll 1
    for (int k = 0; k < 16; k++) {
        long node = n0 + wid * 16 + k;
        float res = 0.f;
        if (node < N_NODES) {
            int st = rstart[node], en = rstart[node + 1];
            int deg = en - st;
            float sdn = sd[node];
            float acc = 0.f, dsum = 0.f;
            if (deg <= 64) {
                int sj = 0; float v = -3.4e38f;
                if (lane < deg) {
                    sj = csr_src[st + lane];
                    v = lrelu(sdn + ss[sj], 0.2f);
                }
                float m = v;
#pragma unroll
                for (int o = 1; o < 64; o <<= 1) m = fmaxf(m, __shfl_xor(m, o, 64));
                float p = (lane < deg) ? __expf(v - m) : 0.f;
                dsum = p;
                int j = 0;
                for (; j + 4 <= deg; j += 4) {
                    float a0 = __shfl(p, j, 64),   a1 = __shfl(p, j+1, 64);
                    float a2 = __shfl(p, j+2, 64), a3 = __shfl(p, j+3, 64);
                    int   s0 = __shfl(sj, j, 64),   s1 = __shfl(sj, j+1, 64);
                    int   s2 = __shfl(sj, j+2, 64), s3 = __shfl(sj, j+3, 64);
                    if (lane < F) {
                        float h0 = bf2f(Hb[(long)s0 * 64 + lane]);
                        float h1 = bf2f(Hb[(long)s1 * 64 + lane]);
                        float h2 = bf2f(Hb[(long)s2 * 64 + lane]);
                        float h3 = bf2f(Hb[(long)s3 * 64 + lane]);
                        acc += a0 * h0; acc += a1 * h1; acc += a2 * h2; acc += a3 * h3;
                    }
                }
                for (; j < deg; j++) {
                    float a = __shfl(p, j, 64);
                    int   s = __shfl(sj, j, 64);
                    if (lane < F) acc += a * bf2f(Hb[(long)s * 64 + lane]);
                }
            } else {
                float m = -3.4e38f;
                for (int base = st; base < en; base += 64) {
                    int cnt = min(64, en - base);
                    float v = -3.4e38f;
                    if (lane < cnt) {
                        int s = csr_src[base + lane];
                        v = lrelu(sdn + ss[s], 0.2f);
                    }
#pragma unroll
                    for (int o = 1; o < 64; o <<= 1) v = fmaxf(v, __shfl_xor(v, o, 64));
                    m = fmaxf(m, v);
                }
                for (int base = st; base < en; base += 64) {
                    int cnt = min(64, en - base);
                    float p = 0.f; int sj = 0;
                    if (lane < cnt) {
                        sj = csr_src[base + lane];
                        float v = lrelu(sdn + ss[sj], 0.2f);
                        p = __expf(v - m);
                    }
                    dsum += p;
                    int j = 0;
                    for (; j + 4 <= cnt; j += 4) {
                        float a0 = __shfl(p, j, 64),   a1 = __shfl(p, j+1, 64);
                        float a2 = __shfl(p, j+2, 64), a3 = __shfl(p, j+3, 64);
                        int   s0 = __shfl(sj, j, 64),   s1 = __shfl(sj, j+1, 64);
                        int   s2 = __shfl(sj, j+2, 64), s3 = __shfl(sj, j+3, 64);
                        if (lane < F) {
                            float h0 = bf2f(Hb[(long)s0 * 64 + lane]);
                            float h1 = bf2f(Hb[(long)s1 * 64 + lane]);
                            float h2 = bf2f(Hb[(long)s2 * 64 + lane]);
                            float h3 = bf2f(Hb[(long)s3 * 64 + lane]);
                            acc += a0 * h0; acc += a1 * h1; acc += a2 * h2; acc += a3 * h3;
                        }
                    }
                    for (; j < cnt; j++) {
                        float a = __shfl(p, j, 64);
                        int   s = __shfl(sj, j, 64);
                        if (lane < F) acc += a * bf2f(Hb[(long)s * 64 + lane]);
                    }
                }
            }
#pragma unroll
            for (int o = 1; o < 64; o <<= 1) dsum += __shfl_xor(dsum, o, 64);
            res = acc / (dsum + 1e-16f);
        }
        if (lane < F) tile[(wid * 16 + k) * (F + 1) + lane] = res + bias[lane];
    }
    __syncthreads();
    for (int idx = t; idx < F * 64; idx += 256) {
        int c = idx / 64, i = idx % 64;
        long n = n0 + i;
        if (n < N_NODES) outT[(long)c * N_NODES + n] = tile[i * (F + 1) + c];
    }
}

// ---------------- final transpose [132][N] -> [N,132] ----------------
__global__ __launch_bounds__(256) void transpose_out(const float* __restrict__ Xt,
                                                     float* __restrict__ out)
{
    __shared__ float tile[64 * 133];
    int t = threadIdx.x;
    long n0 = (long)blockIdx.x * 64;
    int lane = t & 63, cq = t >> 6;
    for (int c = cq; c < 132; c += 4) {
        long n = n0 + lane;
        float v = (n < N_NODES) ? Xt[(long)c * N_NODES + n] : 0.f;
        tile[lane * 133 + c] = v;
    }
    __syncthreads();
    for (int idx = t; idx < 64 * 132; idx += 256) {
        int r = idx / 132, c = idx % 132;
        long n = n0 + r;
        if (n < N_NODES) out[n * 132 + c] = tile[r * 133 + c];
    }
}

// ---------------- bucket-sorted CSR build ----------------
__global__ __launch_bounds__(256) void bkt_hist(const int* __restrict__ dst,
                                                int* __restrict__ bcnt)
{
    __shared__ int lh[NBKT];
    for (int i = threadIdx.x; i < NBKT; i += 256) lh[i] = 0;
    __syncthreads();
    for (long e = (long)blockIdx.x * 256 + threadIdx.x; e < N_EDGES; e += (long)gridDim.x * 256)
        atomicAdd(&lh[dst[e] >> 8], 1);
    __syncthreads();
    for (int i = threadIdx.x; i < NBKT; i += 256)
        if (lh[i]) atomicAdd(&bcnt[i * 16], lh[i]);
}

__global__ void bkt_scan(const int* __restrict__ bcnt, int* __restrict__ boff,
                         int* __restrict__ bcur, int* __restrict__ rstart)
{
    __shared__ int ls[512];
    int t = threadIdx.x;
    int v = (t < NBKT) ? bcnt[t * 16] : 0;
    ls[t] = v; __syncthreads();
    for (int o = 1; o < 512; o <<= 1) {
        int y = (t >= o) ? ls[t - o] : 0;
        __syncthreads();
        ls[t] += y;
        __syncthreads();
    }
    if (t < NBKT) { int ex = ls[t] - v; boff[t] = ex; bcur[t * 16] = ex; }
    if (t == 0) { boff[NBKT] = N_EDGES; rstart[N_NODES] = N_EDGES; }
}

// LDS-privatized scatter: stage edges in LDS, one global atomic per (block,bucket)
__global__ __launch_bounds__(256) void bkt_scatter2(
    const int* __restrict__ src, const int* __restrict__ dst,
    int* __restrict__ bcur, int2* __restrict__ pairs)
{
    __shared__ int lh[NBKT];     // local bucket counts -> then global base offsets
    __shared__ int2 lp[EPB];     // staged edges (25 KB)
    const int t = threadIdx.x;
    const long e0 = (long)blockIdx.x * EPB;
    const int cnt = (int)min((long)EPB, (long)N_EDGES - e0);
    if (cnt <= 0) return;

    for (int i = t; i < NBKT; i += 256) lh[i] = 0;
    __syncthreads();
    for (int i = t; i < cnt; i += 256) {
        int d = dst[e0 + i];
        lp[i] = make_int2(d, src[e0 + i]);
        atomicAdd(&lh[d >> 8], 1);
    }
    __syncthreads();
    // reserve global space per touched bucket (<=391 atomics/block, line-padded)
    for (int b = t; b < NBKT; b += 256) {
        int c = lh[b];
        lh[b] = c ? atomicAdd(&bcur[b * 16], c) : 0;
    }
    __syncthreads();
    // scatter via LDS cursors (lh now holds running global positions)
    for (int i = t; i < cnt; i += 256) {
        int2 p = lp[i];
        int pos = atomicAdd(&lh[p.x >> 8], 1);
        pairs[pos] = p;
    }
}

__global__ __launch_bounds__(256) void bkt_build(const int2* __restrict__ pairs,
                                                 const int* __restrict__ boff,
                                                 int* __restrict__ rstart,
                                                 int* __restrict__ csr_src)
{
    __shared__ int lh[256], sc[256], lbase[256], lcur[256];
    int b = blockIdx.x, t = threadIdx.x;
    int st = boff[b], en = boff[b + 1];
    lh[t] = 0;
    __syncthreads();
    for (int i = st + t; i < en; i += 256)
        atomicAdd(&lh[pairs[i].x & 255], 1);
    __syncthreads();
    int v = lh[t];
    sc[t] = v; __syncthreads();
    for (int o = 1; o < 256; o <<= 1) {
        int y = (t >= o) ? sc[t - o] : 0;
        __syncthreads();
        sc[t] += y;
        __syncthreads();
    }
    int ex = sc[t] - v;
    lbase[t] = st + ex;
    lcur[t] = 0;
    int node = (b << 8) + t;
    if (node < N_NODES) rstart[node] = st + ex;
    __syncthreads();
    for (int i = st + t; i < en; i += 256) {
        int2 p = pairs[i];
        int ld = p.x & 255;
        int pos = lbase[ld] + atomicAdd(&lcur[ld], 1);
        csr_src[pos] = p.y;
    }
}

// ---------------- host helpers ----------------
static void run_dense_block_t(hipStream_t stream, float* Xt, int C0,
                              const float* convW, int WS,
                              const float* gamma, const float* beta,
                              float* gsum, float* gsq, float* psq)
{
    hipMemsetAsync(gsum, 0, 264 * sizeof(float), stream);
    bn_stats_t<<<dim3(C0, 4), 256, 0, stream>>>(Xt, gsum, gsq);
    for (int i = 0; i < 6; i++) {
        int C = C0 + 12 * i;
        dense_conv2<<<NB, 256, 0, stream>>>(Xt, C, C0, i, convW + (size_t)i * 12 * WS, WS,
                                            gamma + (size_t)i * WS, beta + (size_t)i * WS,
                                            gsum, gsq, psq);
    }
}

template<int F>
static void run_gat(hipStream_t stream, const float* XtIn, int K,
                    const float* W, const float* avec, const float* bias,
                    unsigned short* Hb, float* outT,
                    float* sd, float* ss, const int* rstart, const int* csr_src)
{
    gat_gemm<F><<<GG, 256, 0, stream>>>(XtIn, W, avec, K, Hb, sd, ss);
    gat_aggregate2<F><<<GG, 256, 0, stream>>>(rstart, csr_src, sd, ss, Hb, bias, outT);
}

extern "C" void kernel_launch(void* const* d_in, const int* in_sizes, int n_in,
                              void* d_out, int out_size, void* d_ws, size_t ws_size,
                              hipStream_t stream)
{
    const float* x     = (const float*)d_in[0];
    const int*   src   = (const int*)d_in[1];
    const int*   dst   = (const int*)d_in[2];
    const float* w1    = (const float*)d_in[3];
    const float* b1    = (const float*)d_in[4];
    const float* w2    = (const float*)d_in[5];
    const float* b2    = (const float*)d_in[6];
    const float* w3    = (const float*)d_in[7];
    const float* b3    = (const float*)d_in[8];
    const float* conv1 = (const float*)d_in[9];
    const float* bn1g  = (const float*)d_in[10];
    const float* bn1b  = (const float*)d_in[11];
    const float* g1w   = (const float*)d_in[12];
    const float* g1a   = (const float*)d_in[13];
    const float* g1b   = (const float*)d_in[14];
    const float* conv2 = (const float*)d_in[15];
    const float* bn2g  = (const float*)d_in[16];
    const float* bn2b  = (const float*)d_in[17];
    const float* g2w   = (const float*)d_in[18];
    const float* g2a   = (const float*)d_in[19];
    const float* g2b   = (const float*)d_in[20];
    const float* conv3 = (const float*)d_in[21];
    const float* bn3g  = (const float*)d_in[22];
    const float* bn3b  = (const float*)d_in[23];
    float* out = (float*)d_out;

    char* ws = (char*)d_ws;
    size_t off = 0;
    auto alloc = [&](size_t bytes) -> void* {
        void* p = ws + off;
        off += (bytes + 255) & ~(size_t)255;
        return p;
    };
    float*    h      = (float*)alloc((size_t)N_NODES * 256 * 4); // overlays: Hb + Xt3
    float*    Xt1    = (float*)alloc((size_t)96  * N_NODES * 4);
    float*    Xt2    = (float*)alloc((size_t)120 * N_NODES * 4);
    int*      csr_src= (int*)alloc((size_t)N_EDGES * 4);
    int2*     pairs  = (int2*)alloc((size_t)N_EDGES * 8);
    int*      rstart = (int*)alloc((size_t)(N_NODES + 1) * 4);
    int*      bcnt   = (int*)alloc((size_t)NBKT * 16 * 4);
    int*      bcur   = (int*)alloc((size_t)NBKT * 16 * 4);
    int*      boff   = (int*)alloc((size_t)(NBKT + 1) * 4);
    float*    sd     = (float*)alloc((size_t)N_NODES * 4);
    float*    ss     = (float*)alloc((size_t)N_NODES * 4);
    float*    gsum   = (float*)alloc(264 * 4);
    float*    gsq    = gsum + 132;
    float*    psq    = (float*)alloc((size_t)2 * 6 * 12 * NB * 4);
    unsigned short* wt1h = (unsigned short*)alloc(256 * 64  * 2);
    unsigned short* wt1l = (unsigned short*)alloc(256 * 64  * 2);
    unsigned short* wt2h = (unsigned short*)alloc(256 * 256 * 2);
    unsigned short* wt2l = (unsigned short*)alloc(256 * 256 * 2);
    unsigned short* wt3h = (unsigned short*)alloc(32  * 256 * 2);
    unsigned short* wt3l = (unsigned short*)alloc(32  * 256 * 2);

    // overlays in h (102.4 MB):
    unsigned short* Hb  = (unsigned short*)h;            // [N][64] bf16 = 12.8 MB (128B rows)
    float* Xt3 = (float*)((char*)h + (size_t)16 * 1024 * 1024); // [132][N] f32 = 52.8 MB

    // ---- bucket-sorted CSR by dst (shared by both GATs), payload = src values ----
    hipMemsetAsync(bcnt, 0, (size_t)NBKT * 16 * 4, stream);
    bkt_hist<<<512, 256, 0, stream>>>(dst, bcnt);
    bkt_scan<<<1, 512, 0, stream>>>(bcnt, boff, bcur, rstart);
    bkt_scatter2<<<SCG, 256, 0, stream>>>(src, dst, bcur, pairs);
    bkt_build<<<NBKT, 256, 0, stream>>>(pairs, boff, rstart, csr_src);

    // ---- weight prep (f32 -> transposed hi/lo bf16) ----
    cvt_wT_split<<<(256 * 64  + 255) / 256, 256, 0, stream>>>(w1, wt1h, wt1l, 64,  256, 256);
    cvt_wT_split<<<(256 * 256 + 255) / 256, 256, 0, stream>>>(w2, wt2h, wt2l, 256, 256, 256);
    cvt_wT_split<<<(32  * 256 + 255) / 256, 256, 0, stream>>>(w3, wt3h, wt3l, 256, 24,  32);

    // ---- fully-fused MLP (x -> L1 -> L2 -> L3 -> Xt1, activations stay in LDS) ----
    mlp_fused<<<GG, 256, 0, stream>>>(x, wt1h, wt1l, b1, wt2h, wt2l, b2,
                                      wt3h, wt3l, b3, Xt1);

    // ---- dense block 1 (24 -> 96, channel-major) ----
    run_dense_block_t(stream, Xt1, 24, conv1, 84, bn1g, bn1b, gsum, gsq, psq);

    // ---- GAT 1 (96 -> 48), output transposed into Xt2 rows 0..47 ----
    run_gat<48>(stream, Xt1, 96, g1w, g1a, g1b, Hb, Xt2, sd, ss, rstart, csr_src);

    // ---- dense block 2 (48 -> 120) ----
    run_dense_block_t(stream, Xt2, 48, conv2, 108, bn2g, bn2b, gsum, gsq, psq);

    // ---- GAT 2 (120 -> 60), output transposed into Xt3 rows 0..59 ----
    run_gat<60>(stream, Xt2, 120, g2w, g2a, g2b, Hb, Xt3, sd, ss, rstart, csr_src);

    // ---- dense block 3 (60 -> 132) ----
    run_dense_block_t(stream, Xt3, 60, conv3, 120, bn3g, bn3b, gsum, gsq, psq);

    // ---- final transpose to row-major d_out ----
    transpose_out<<<GG, 256, 0, stream>>>(Xt3, out);
}